// Round 11
// baseline (550.976 us; speedup 1.0000x reference)
//
#include <hip/hip_runtime.h>

// TransformerBlock fused pipeline for MI355X (gfx950).
// SEQ=2048, D_MODEL=2048, H=16, DK=DV=128, DFF=8192. fp32 in/out.
//
// R11: split-KV reverted (regressed: supply/cap rounds -> only 26% occ, and
// occupancy was not the binder anyway). Flash rebuilt on the T3/T4 schedule:
// KVBLK=32, K/V double-buffered (2x24KB) + dedicated P (4KB) = 52KB, per-tile
// {compute -> GBAR -> STAGE(t+2) -> vmcnt(6) -> GBAR} -- the vmcnt(0) drain
// never appears in the main loop. Everything else R9-exact.

typedef __bf16 bf16;
typedef __attribute__((ext_vector_type(8))) __bf16 bf16x8;
typedef __attribute__((ext_vector_type(4))) __bf16 bf16x4;
typedef __attribute__((ext_vector_type(4))) float f32x4;

#define MFMA(a, b, c) __builtin_amdgcn_mfma_f32_16x16x32_bf16((a), (b), (c), 0, 0, 0)
#define NEG_INF (-3.402823466e38f)

__device__ __forceinline__ void cp16(void* lds, const void* g) {
  __builtin_amdgcn_global_load_lds(
      (const __attribute__((address_space(1))) unsigned int*)g,
      (__attribute__((address_space(3))) unsigned int*)lds, 16, 0, 0);
}

#define SBAR() __builtin_amdgcn_sched_barrier(0)
#define GBAR()                              \
  do {                                      \
    asm volatile("" ::: "memory");          \
    __builtin_amdgcn_s_barrier();           \
    asm volatile("" ::: "memory");          \
  } while (0)
#define LGKM0()                                         \
  do {                                                  \
    asm volatile("s_waitcnt lgkmcnt(0)" ::: "memory");  \
    __builtin_amdgcn_sched_barrier(0);                  \
  } while (0)
#define VMC6()                                          \
  do {                                                  \
    asm volatile("s_waitcnt vmcnt(6)" ::: "memory");    \
    __builtin_amdgcn_sched_barrier(0);                  \
  } while (0)

// ---------------- converts ----------------

__global__ void k_split_x(const float* __restrict__ x, bf16* __restrict__ xh,
                          bf16* __restrict__ xl) {
  int i = blockIdx.x * 256 + threadIdx.x;
  f32x4 v = ((const f32x4*)x)[i];
  bf16x4 h, l;
#pragma unroll
  for (int j = 0; j < 4; ++j) {
    bf16 hi = (bf16)v[j];
    h[j] = hi;
    l[j] = (bf16)(v[j] - (float)hi);
  }
  ((bf16x4*)xh)[i] = h;
  ((bf16x4*)xl)[i] = l;
}

template <bool SPLIT>
__global__ void k_tcvt(const float* __restrict__ in, bf16* __restrict__ oh,
                       bf16* __restrict__ ol, int R, int C) {
  __shared__ float t[64][65];
  long zoff = (long)blockIdx.z * R * C;
  int c0 = blockIdx.x * 64, r0 = blockIdx.y * 64;
  int cc = threadIdx.x & 63, rr = threadIdx.x >> 6;
#pragma unroll
  for (int i = 0; i < 16; ++i) {
    int r = i * 4 + rr;
    t[r][cc] = in[zoff + (long)(r0 + r) * C + c0 + cc];
  }
  __syncthreads();
#pragma unroll
  for (int i = 0; i < 16; ++i) {
    int orow = i * 4 + rr;
    float v = t[cc][orow];
    long oidx = zoff + (long)(c0 + orow) * R + r0 + cc;
    bf16 hi = (bf16)v;
    oh[oidx] = hi;
    if (SPLIT) ol[oidx] = (bf16)(v - (float)hi);
  }
}

// combine 4 fp32 partials -> bf16
__global__ void k_combine4(const float* __restrict__ p, long pstr,
                           bf16* __restrict__ o) {
  int i = blockIdx.x * 256 + threadIdx.x;
  f32x4 v = ((const f32x4*)p)[i];
#pragma unroll
  for (int zz = 1; zz < 4; ++zz) v += ((const f32x4*)(p + zz * pstr))[i];
  bf16x4 ob;
#pragma unroll
  for (int j = 0; j < 4; ++j) ob[j] = (bf16)v[j];
  ((bf16x4*)o)[i] = ob;
}

// ---------------- 8-phase 256^2 GEMM (R6 value-verified) ----------------
template <int EPI>
__global__ __launch_bounds__(512, 1) void k_gemm8(
    const bf16* __restrict__ A, const bf16* __restrict__ B,
    float* __restrict__ Cf, bf16* __restrict__ Cb,
    const float* __restrict__ bias, int M, int N, int K, int nsplit) {
  __shared__ char lds[131072];
  const int tid = threadIdx.x, w = tid >> 6, l = tid & 63;
  const int l16 = l & 15, lg = l >> 4;
  const int wr = w >> 2, wc = w & 3;
  const long bm0 = (long)blockIdx.y * 256, bn0 = (long)blockIdx.x * 256;
  const int z = blockIdx.z;
  const int ksz = K / nsplit, kbeg = z * ksz;
  const int nt = ksz >> 6;
  const long lK = K;

  const int srow = w * 8 + (l >> 3);
  const int sslot = (l & 7) ^ (l >> 3);

  auto STAGE = [&](int bufp, int isB, int h, int tt) {
    int tc = tt < nt ? tt : nt - 1;
    char* dst = lds + bufp * 65536 + isB * 32768 + h * 16384 + w * 1024;
    const bf16* G = isB ? B : A;
    long r0 = (isB ? bn0 : bm0) + h * 128 + srow;
    const bf16* src = G + r0 * lK + kbeg + tc * 64 + sslot * 8;
    cp16(dst, src);
    cp16(dst + 8192, src + 64 * lK);
  };
  auto LDA = [&](int bufp, int mf, int ks) -> bf16x8 {
    int inrow = (mf & 3) * 32 + wr * 16 + l16;
    int byo = bufp * 65536 + (mf >> 2) * 16384 + inrow * 128 +
              ((((ks << 2) + lg) ^ (inrow & 7)) << 4);
    return *(const bf16x8*)(lds + byo);
  };
  auto LDB = [&](int bufp, int nf, int ks) -> bf16x8 {
    int inrow = (nf & 1) * 64 + wc * 16 + l16;
    int byo = bufp * 65536 + 32768 + (nf >> 1) * 16384 + inrow * 128 +
              ((((ks << 2) + lg) ^ (inrow & 7)) << 4);
    return *(const bf16x8*)(lds + byo);
  };

  f32x4 acc[8][4];
#pragma unroll
  for (int mf = 0; mf < 8; ++mf)
#pragma unroll
    for (int nf = 0; nf < 4; ++nf)
#pragma unroll
      for (int j = 0; j < 4; ++j) acc[mf][nf][j] = 0.f;

  STAGE(0, 0, 0, 0);
  STAGE(0, 1, 0, 0);
  STAGE(0, 0, 1, 0);
  STAGE(0, 1, 1, 0);
  STAGE(1, 1, 0, 1);
  STAGE(1, 0, 1, 1);
  STAGE(1, 1, 1, 1);
  SBAR();
  VMC6();
  GBAR();

  bf16x8 a[4][2], b[2][2];
  for (int t = 0; t < nt; ++t) {
    const int cb = t & 1, nb = cb ^ 1;
#pragma unroll
    for (int mf = 0; mf < 4; ++mf)
#pragma unroll
      for (int ks = 0; ks < 2; ++ks) a[mf][ks] = LDA(cb, mf, ks);
#pragma unroll
    for (int nf = 0; nf < 2; ++nf)
#pragma unroll
      for (int ks = 0; ks < 2; ++ks) b[nf][ks] = LDB(cb, nf, ks);
    STAGE(nb, 0, 0, t + 1);
    SBAR();
    GBAR();
    LGKM0();
    __builtin_amdgcn_s_setprio(1);
#pragma unroll
    for (int mf = 0; mf < 4; ++mf)
#pragma unroll
      for (int nf = 0; nf < 2; ++nf)
#pragma unroll
        for (int ks = 0; ks < 2; ++ks)
          acc[mf][nf] = MFMA(a[mf][ks], b[nf][ks], acc[mf][nf]);
    __builtin_amdgcn_s_setprio(0);
    GBAR();
#pragma unroll
    for (int mf = 0; mf < 4; ++mf)
#pragma unroll
      for (int ks = 0; ks < 2; ++ks) a[mf][ks] = LDA(cb, mf + 4, ks);
    STAGE(cb, 1, 0, t + 2);
    SBAR();
    GBAR();
    LGKM0();
    __builtin_amdgcn_s_setprio(1);
#pragma unroll
    for (int mf = 0; mf < 4; ++mf)
#pragma unroll
      for (int nf = 0; nf < 2; ++nf)
#pragma unroll
        for (int ks = 0; ks < 2; ++ks)
          acc[mf + 4][nf] = MFMA(a[mf][ks], b[nf][ks], acc[mf + 4][nf]);
    __builtin_amdgcn_s_setprio(0);
    GBAR();
#pragma unroll
    for (int nf = 0; nf < 2; ++nf)
#pragma unroll
      for (int ks = 0; ks < 2; ++ks) b[nf][ks] = LDB(cb, nf + 2, ks);
    GBAR();
    LGKM0();
    __builtin_amdgcn_s_setprio(1);
#pragma unroll
    for (int mf = 0; mf < 4; ++mf)
#pragma unroll
      for (int nf = 0; nf < 2; ++nf)
#pragma unroll
        for (int ks = 0; ks < 2; ++ks)
          acc[mf + 4][nf + 2] = MFMA(a[mf][ks], b[nf][ks], acc[mf + 4][nf + 2]);
    __builtin_amdgcn_s_setprio(0);
    GBAR();
#pragma unroll
    for (int mf = 0; mf < 4; ++mf)
#pragma unroll
      for (int ks = 0; ks < 2; ++ks) a[mf][ks] = LDA(cb, mf, ks);
    STAGE(cb, 0, 1, t + 2);
    STAGE(cb, 1, 1, t + 2);
    SBAR();
    VMC6();
    GBAR();
    LGKM0();
    __builtin_amdgcn_s_setprio(1);
#pragma unroll
    for (int mf = 0; mf < 4; ++mf)
#pragma unroll
      for (int nf = 0; nf < 2; ++nf)
#pragma unroll
        for (int ks = 0; ks < 2; ++ks)
          acc[mf][nf + 2] = MFMA(a[mf][ks], b[nf][ks], acc[mf][nf + 2]);
    __builtin_amdgcn_s_setprio(0);
    GBAR();
  }
  asm volatile("s_waitcnt vmcnt(0) lgkmcnt(0)" ::: "memory");

#pragma unroll
  for (int mf = 0; mf < 8; ++mf)
#pragma unroll
    for (int nf = 0; nf < 4; ++nf) {
      long col = bn0 + nf * 64 + wc * 16 + l16;
      float bv = (EPI == 2) ? bias[col] : 0.f;
#pragma unroll
      for (int jj = 0; jj < 4; ++jj) {
        long row = bm0 + mf * 32 + wr * 16 + lg * 4 + jj;
        float v = acc[mf][nf][jj];
        if (EPI == 0) {
          Cf[(long)z * M * N + row * N + col] = v;
        } else {
          v = fmaxf(v + bv, 0.f);
          Cb[row * N + col] = (bf16)v;
        }
      }
    }
}

// ---------------- 8-phase split-precision GEMM (QK projection) -------------
__global__ __launch_bounds__(512, 1) void k_split8(
    const bf16* __restrict__ Ah_g, const bf16* __restrict__ Al_g,
    const bf16* __restrict__ Bh_g, const bf16* __restrict__ Bl_g,
    bf16* __restrict__ Ch, bf16* __restrict__ Cl,
    int M, int N, int K, float scale, int scale_ncols) {
  __shared__ char lds[98304];
  const int tid = threadIdx.x, w = tid >> 6, l = tid & 63;
  const int l16 = l & 15, lg = l >> 4;
  const int wr = w >> 2, wc = w & 3;
  const long bm0 = (long)blockIdx.y * 128, bn0 = (long)blockIdx.x * 256;
  const int nt = K >> 5;
  const long lK = K;

  const int srcrow = tid >> 2;
  const int ss = (tid & 3) ^ ((tid >> 3) & 3);

  auto STG_A = [&](int bufp, int isLo, int tt) {
    int tc = tt < nt ? tt : nt - 1;
    char* dst = lds + bufp * 49152 + isLo * 8192 + tid * 16;
    const bf16* G = isLo ? Al_g : Ah_g;
    cp16(dst, &G[(bm0 + srcrow) * lK + tc * 32 + ss * 8]);
  };
  auto STG_B = [&](int bufp, int isLo, int half, int tt) {
    int tc = tt < nt ? tt : nt - 1;
    char* dst = lds + bufp * 49152 + 16384 + isLo * 16384 + half * 8192 + tid * 16;
    const bf16* G = isLo ? Bl_g : Bh_g;
    cp16(dst, &G[(bn0 + half * 128 + srcrow) * lK + tc * 32 + ss * 8]);
  };
  auto LDA8 = [&](int bufp, int mf, int isLo) -> bf16x8 {
    int row = mf * 32 + wr * 16 + l16;
    int byo = bufp * 49152 + isLo * 8192 + row * 64 +
              ((lg ^ ((row >> 1) & 3)) << 4);
    return *(const bf16x8*)(lds + byo);
  };
  auto LDB8 = [&](int bufp, int nf, int isLo) -> bf16x8 {
    int row = nf * 64 + wc * 16 + l16;
    int byo = bufp * 49152 + 16384 + isLo * 16384 + row * 64 +
              ((lg ^ ((row >> 1) & 3)) << 4);
    return *(const bf16x8*)(lds + byo);
  };

  f32x4 acc[4][4];
#pragma unroll
  for (int mf = 0; mf < 4; ++mf)
#pragma unroll
    for (int nf = 0; nf < 4; ++nf)
#pragma unroll
      for (int j = 0; j < 4; ++j) acc[mf][nf][j] = 0.f;

  STG_B(0, 0, 0, 0); STG_B(0, 1, 0, 0);
  STG_A(0, 0, 0);    STG_A(0, 1, 0);
  STG_B(0, 0, 1, 0); STG_B(0, 1, 1, 0);
  STG_B(1, 0, 0, 1); STG_B(1, 1, 0, 1);
  STG_A(1, 0, 1);    STG_A(1, 1, 1);
  STG_B(1, 0, 1, 1); STG_B(1, 1, 1, 1);
  SBAR();
  VMC6();
  GBAR();

  bf16x8 ah[4], al[4], bh[2], bl[2];
  for (int t = 0; t < nt; ++t) {
    const int cb = t & 1;
    // P1
#pragma unroll
    for (int mf = 0; mf < 2; ++mf) {
      ah[mf] = LDA8(cb, mf, 0);
      al[mf] = LDA8(cb, mf, 1);
    }
#pragma unroll
    for (int nf = 0; nf < 2; ++nf) {
      bh[nf] = LDB8(cb, nf, 0);
      bl[nf] = LDB8(cb, nf, 1);
    }
    SBAR();
    GBAR();
    LGKM0();
    __builtin_amdgcn_s_setprio(1);
#pragma unroll
    for (int mf = 0; mf < 2; ++mf)
#pragma unroll
      for (int nf = 0; nf < 2; ++nf) {
        acc[mf][nf] = MFMA(ah[mf], bh[nf], acc[mf][nf]);
        acc[mf][nf] = MFMA(ah[mf], bl[nf], acc[mf][nf]);
        acc[mf][nf] = MFMA(al[mf], bh[nf], acc[mf][nf]);
      }
    __builtin_amdgcn_s_setprio(0);
    GBAR();
    // P2
#pragma unroll
    for (int mf = 2; mf < 4; ++mf) {
      ah[mf] = LDA8(cb, mf, 0);
      al[mf] = LDA8(cb, mf, 1);
    }
    STG_B(cb, 0, 0, t + 2);
    STG_B(cb, 1, 0, t + 2);
    SBAR();
    GBAR();
    LGKM0();
    __builtin_amdgcn_s_setprio(1);
#pragma unroll
    for (int mf = 2; mf < 4; ++mf)
#pragma unroll
      for (int nf = 0; nf < 2; ++nf) {
        acc[mf][nf] = MFMA(ah[mf], bh[nf], acc[mf][nf]);
        acc[mf][nf] = MFMA(ah[mf], bl[nf], acc[mf][nf]);
        acc[mf][nf] = MFMA(al[mf], bh[nf], acc[mf][nf]);
      }
    __builtin_amdgcn_s_setprio(0);
    GBAR();
    // P3
#pragma unroll
    for (int nf = 0; nf < 2; ++nf) {
      bh[nf] = LDB8(cb, nf + 2, 0);
      bl[nf] = LDB8(cb, nf + 2, 1);
    }
    STG_A(cb, 0, t + 2);
    STG_A(cb, 1, t + 2);
    SBAR();
    GBAR();
    LGKM0();
    __builtin_amdgcn_s_setprio(1);
#pragma unroll
    for (int mf = 2; mf < 4; ++mf)
#pragma unroll
      for (int nf = 0; nf < 2; ++nf) {
        acc[mf][nf + 2] = MFMA(ah[mf], bh[nf], acc[mf][nf + 2]);
        acc[mf][nf + 2] = MFMA(ah[mf], bl[nf], acc[mf][nf + 2]);
        acc[mf][nf + 2] = MFMA(al[mf], bh[nf], acc[mf][nf + 2]);
      }
    __builtin_amdgcn_s_setprio(0);
    GBAR();
    // P4
    STG_B(cb, 0, 1, t + 2);
    STG_B(cb, 1, 1, t + 2);
    SBAR();
    VMC6();
    GBAR();
    __builtin_amdgcn_s_setprio(1);
#pragma unroll
    for (int mf = 0; mf < 2; ++mf)
#pragma unroll
      for (int nf = 0; nf < 2; ++nf) {
        acc[mf][nf + 2] = MFMA(ah[mf], bh[nf], acc[mf][nf + 2]);
        acc[mf][nf + 2] = MFMA(ah[mf], bl[nf], acc[mf][nf + 2]);
        acc[mf][nf + 2] = MFMA(al[mf], bh[nf], acc[mf][nf + 2]);
      }
    __builtin_amdgcn_s_setprio(0);
    GBAR();
  }
  asm volatile("s_waitcnt vmcnt(0) lgkmcnt(0)" ::: "memory");

#pragma unroll
  for (int mf = 0; mf < 4; ++mf)
#pragma unroll
    for (int nf = 0; nf < 4; ++nf) {
      long col = bn0 + nf * 64 + wc * 16 + l16;
      float sc = (col < scale_ncols) ? scale : 1.0f;
#pragma unroll
      for (int j = 0; j < 4; ++j) {
        long row = bm0 + mf * 32 + wr * 16 + lg * 4 + j;
        float v = acc[mf][nf][j] * sc;
        bf16 hi = (bf16)v;
        Ch[row * N + col] = hi;
        Cl[row * N + col] = (bf16)(v - (float)hi);
      }
    }
}

// ---------------- flash attention (KVBLK=32, dbuf K/V, counted vmcnt) ------
// LDS 52KB: 2 bufs x {Kh[32][128] 8K, Kl 8K, Vt[128][32] 8K} + P[64][32] 4K.
// Per tile: compute(buf cur) -> GBAR -> STAGE(cur, t+2) -> vmcnt(6) -> GBAR.
// vmcnt never drains to 0 in the loop (T3/T4). P is per-wave (no barrier).
__global__ __launch_bounds__(256, 3) void k_flash(
    const bf16* __restrict__ Qh, const bf16* __restrict__ Ql,
    const bf16* __restrict__ Kh, const bf16* __restrict__ Kl,
    const bf16* __restrict__ Vt, bf16* __restrict__ Oc) {
  __shared__ bf16 sm[26624];  // 53248 B
  bf16* sP = sm + 24576;      // byte offset 49152
  const int tid = threadIdx.x, w = tid >> 6, l = tid & 63;
  const int l16 = l & 15, lg = l >> 4;
  const int head = blockIdx.y;
  const long q0 = (long)blockIdx.x * 64;

  bf16x8 qh_r[4], ql_r[4];
#pragma unroll
  for (int kk = 0; kk < 4; ++kk) {
    long off = (q0 + w * 16 + l16) * 4096 + head * 128 + kk * 32 + lg * 8;
    qh_r[kk] = *(const bf16x8*)&Qh[off];
    ql_r[kk] = *(const bf16x8*)&Ql[off];
  }

  // stage one 32-KV tile into buffer `buf` (6 cp16/thread)
  auto STAGE = [&](int buf, int kt) {
    char* base = (char*)sm + buf * 24576;
#pragma unroll
    for (int i = 0; i < 2; ++i) {
      int u = i * 256 + tid;                 // 0..511 16B-units
      int rk = u >> 4, sk = (u & 15) ^ (rk & 7);
      long ko = (long)(kt + rk) * 4096 + head * 128 + sk * 8;
      cp16(base + u * 16, &Kh[ko]);
      cp16(base + 8192 + u * 16, &Kl[ko]);
      int rv = u >> 2, sv = (u & 3) ^ (rv & 3);
      long vo = (long)(head * 128 + rv) * 2048 + kt + sv * 8;
      cp16(base + 16384 + u * 16, &Vt[vo]);
    }
  };

  f32x4 acc_o[8];
#pragma unroll
  for (int n = 0; n < 8; ++n)
#pragma unroll
    for (int j = 0; j < 4; ++j) acc_o[n][j] = 0.f;
  float mrow[4], lrow[4];
#pragma unroll
  for (int j = 0; j < 4; ++j) {
    mrow[j] = NEG_INF;
    lrow[j] = 0.f;
  }

  STAGE(0, 0);
  STAGE(1, 32);
  SBAR();
  VMC6();   // tile0 landed; tile1's 6 in flight
  GBAR();

  for (int t = 0; t < 64; ++t) {
    const int cur = t & 1;
    const char* kb = (const char*)sm + cur * 24576;

    // QK^T (3-pass) on 32 cols
    f32x4 s[2];
#pragma unroll
    for (int n = 0; n < 2; ++n)
#pragma unroll
      for (int j = 0; j < 4; ++j) s[n][j] = 0.f;
    __builtin_amdgcn_s_setprio(1);
#pragma unroll
    for (int kk = 0; kk < 4; ++kk) {
      bf16x8 bh[2], bl[2];
#pragma unroll
      for (int n = 0; n < 2; ++n) {
        int r = n * 16 + l16;
        int byo = r * 256 + (((kk * 4 + lg) ^ (r & 7)) << 4);
        bh[n] = *(const bf16x8*)(kb + byo);
        bl[n] = *(const bf16x8*)(kb + 8192 + byo);
      }
#pragma unroll
      for (int n = 0; n < 2; ++n) {
        s[n] = MFMA(qh_r[kk], bh[n], s[n]);
        s[n] = MFMA(qh_r[kk], bl[n], s[n]);
        s[n] = MFMA(ql_r[kk], bh[n], s[n]);
      }
    }
    __builtin_amdgcn_s_setprio(0);

    // online softmax (P rows are per-wave: no barrier needed)
#pragma unroll
    for (int j = 0; j < 4; ++j) {
      float mx = fmaxf(s[0][j], s[1][j]);
      mx = fmaxf(mx, __shfl_xor(mx, 1));
      mx = fmaxf(mx, __shfl_xor(mx, 2));
      mx = fmaxf(mx, __shfl_xor(mx, 4));
      mx = fmaxf(mx, __shfl_xor(mx, 8));
      float mo = mrow[j];
      float mn = fmaxf(mo, mx);
      mrow[j] = mn;
      float f = __expf(mo - mn);
      int prow = w * 16 + lg * 4 + j;
      float ssum = 0.f;
#pragma unroll
      for (int n = 0; n < 2; ++n) {
        float p = __expf(s[n][j] - mn);
        ssum += p;
        int byo = prow * 64 + (((n * 16 + l16) * 2) ^ ((prow & 3) << 4));
        *(bf16*)((char*)sP + byo) = (bf16)p;
      }
      ssum += __shfl_xor(ssum, 1);
      ssum += __shfl_xor(ssum, 2);
      ssum += __shfl_xor(ssum, 4);
      ssum += __shfl_xor(ssum, 8);
      lrow[j] = lrow[j] * f + ssum;
#pragma unroll
      for (int n = 0; n < 8; ++n) acc_o[n][j] *= f;
    }

    // PV: acc_o += P[16 x 32] @ V[32 x 128]  (k=32 -> single A-frag)
    __builtin_amdgcn_s_setprio(1);
    bf16x8 pa, bv[8];
    {
      int r = w * 16 + l16;
      int byo = r * 64 + ((lg ^ (r & 3)) << 4);
      pa = *(const bf16x8*)((const char*)sP + byo);
    }
#pragma unroll
    for (int n = 0; n < 8; ++n) {
      int r = n * 16 + l16;
      int byo = r * 64 + ((lg ^ (r & 3)) << 4);
      bv[n] = *(const bf16x8*)(kb + 16384 + byo);
    }
#pragma unroll
    for (int n = 0; n < 8; ++n) acc_o[n] = MFMA(pa, bv[n], acc_o[n]);
    __builtin_amdgcn_s_setprio(0);

    GBAR();  // all waves done reading buf[cur]
    int nkt = (t + 2 < 64) ? (t + 2) * 32 : t * 32;  // clamp: dummy reload
    STAGE(cur, nkt);
    SBAR();
    VMC6();  // tile t+1 (buf cur^1) fully landed; t+2's 6 in flight
    GBAR();
  }
  asm volatile("s_waitcnt vmcnt(0) lgkmcnt(0)" ::: "memory");

#pragma unroll
  for (int j = 0; j < 4; ++j) {
    float rinv = 1.f / lrow[j];
    long row = q0 + w * 16 + lg * 4 + j;
#pragma unroll
    for (int n = 0; n < 8; ++n)
      Oc[row * 2048 + head * 128 + n * 16 + l16] = (bf16)(acc_o[n][j] * rinv);
  }
}

// ---------------- residual + np partials + LayerNorm ----------------
__global__ __launch_bounds__(256) void k_add_ln(
    const float* __restrict__ a, const float* __restrict__ p, long pstr,
    int np, const float* __restrict__ bias, const float* __restrict__ g,
    const float* __restrict__ be, float* __restrict__ o32,
    bf16* __restrict__ obf) {
  __shared__ float red[8];
  int row = blockIdx.x, tid = threadIdx.x;
  const float* pa = a + (long)row * 2048;
  f32x4 v[2];
  float sum = 0.f, sq = 0.f;
#pragma unroll
  for (int i = 0; i < 2; ++i) {
    int idx = i * 1024 + tid * 4;
    v[i] = *(const f32x4*)(pa + idx);
    for (int zz = 0; zz < np; ++zz)
      v[i] += *(const f32x4*)(p + zz * pstr + (long)row * 2048 + idx);
    if (bias != nullptr) v[i] += *(const f32x4*)(bias + idx);
#pragma unroll
    for (int j = 0; j < 4; ++j) {
      sum += v[i][j];
      sq += v[i][j] * v[i][j];
    }
  }
#pragma unroll
  for (int o = 1; o < 64; o <<= 1) {
    sum += __shfl_xor(sum, o);
    sq += __shfl_xor(sq, o);
  }
  int w = tid >> 6;
  if ((tid & 63) == 0) {
    red[w * 2] = sum;
    red[w * 2 + 1] = sq;
  }
  __syncthreads();
  sum = red[0] + red[2] + red[4] + red[6];
  sq = red[1] + red[3] + red[5] + red[7];
  float mu = sum * (1.f / 2048.f);
  float var = sq * (1.f / 2048.f) - mu * mu;
  float rs = rsqrtf(var + 1e-5f);
#pragma unroll
  for (int i = 0; i < 2; ++i) {
    int idx = i * 1024 + tid * 4;
    f32x4 vg = *(const f32x4*)(g + idx);
    f32x4 vb = *(const f32x4*)(be + idx);
    f32x4 o;
#pragma unroll
    for (int j = 0; j < 4; ++j) o[j] = (v[i][j] - mu) * rs * vg[j] + vb[j];
    *(f32x4*)(o32 + (long)row * 2048 + idx) = o;
    if (obf != nullptr) {
      bf16x4 ob;
#pragma unroll
      for (int j = 0; j < 4; ++j) ob[j] = (bf16)o[j];
      *(bf16x4*)(obf + (long)row * 2048 + idx) = ob;
    }
  }
}

// ---------------- launch ----------------
extern "C" void kernel_launch(void* const* d_in, const int* in_sizes, int n_in,
                              void* d_out, int out_size, void* d_ws, size_t ws_size,
                              hipStream_t stream) {
  const float* x    = (const float*)d_in[0];
  const float* wq   = (const float*)d_in[1];
  const float* wk   = (const float*)d_in[2];
  const float* wv   = (const float*)d_in[3];
  const float* wp   = (const float*)d_in[4];
  const float* g1   = (const float*)d_in[5];
  const float* b1   = (const float*)d_in[6];
  const float* fc1w = (const float*)d_in[7];
  const float* fc1b = (const float*)d_in[8];
  const float* fc2w = (const float*)d_in[9];
  const float* fc2b = (const float*)d_in[10];
  const float* g2   = (const float*)d_in[11];
  const float* b2   = (const float*)d_in[12];
  float* out = (float*)d_out;

  char* ws = (char*)d_ws;
  const size_t MB = 1024 * 1024;
  if (ws_size < 216 * MB) return;
  const long W4M = 4L * 1024 * 1024;

  // ADJACENCY CONSTRAINT: qk_bh = [wq^T | wk^T] hi as ONE [4096][2048];
  // qk_bl likewise lo (split8's B operands span both).
  bf16* xh    = (bf16*)(ws + 0 * MB);
  bf16* xl    = (bf16*)(ws + 8 * MB);
  bf16* qk_bh = (bf16*)(ws + 16 * MB);   // 16MB
  bf16* qk_bl = (bf16*)(ws + 32 * MB);   // 16MB
  bf16* wvt   = (bf16*)(ws + 48 * MB);
  bf16* wpt   = (bf16*)(ws + 56 * MB);
  bf16* fc1t  = (bf16*)(ws + 64 * MB);   // 32MB
  bf16* fc2t  = (bf16*)(ws + 96 * MB);   // 32MB
  float* vtp  = (float*)(ws + 128 * MB); // 4x16MB vt partials
  bf16* vtb   = (bf16*)(ws + 192 * MB);  // 8MB
  bf16* qkh   = (bf16*)(ws + 128 * MB);  // 16MB (vtp dead)
  bf16* qkl   = (bf16*)(ws + 144 * MB);  // 16MB
  bf16* cc    = (bf16*)(ws + 200 * MB);  // 8MB concat
  float* aop  = (float*)(ws + 128 * MB); // 4x16MB (qk dead post-flash)
  float* h32  = (float*)(ws + 192 * MB); // 16MB (vtb dead post-flash)
  bf16*  hbf  = (bf16*)(ws + 208 * MB);  // 8MB
  bf16*  ff1  = (bf16*)(ws + 128 * MB);  // 32MB (aop dead after LN1)
  float* ffp  = (float*)(ws + 0 * MB);   // 4x16MB (x/qk_b dead)
  const long PSTR = 4194304L;

  // converts
  k_split_x<<<4096, 256, 0, stream>>>(x, xh, xl);
  k_tcvt<true ><<<dim3(2, 32, 16), 256, 0, stream>>>(wq, qk_bh, qk_bl, 2048, 128);
  k_tcvt<true ><<<dim3(2, 32, 16), 256, 0, stream>>>(wk, qk_bh + W4M, qk_bl + W4M,
                                                     2048, 128);
  k_tcvt<false><<<dim3(2, 32, 16), 256, 0, stream>>>(wv, wvt, nullptr, 2048, 128);
  k_tcvt<false><<<dim3(32, 32, 1), 256, 0, stream>>>(wp, wpt, nullptr, 2048, 2048);
  k_tcvt<false><<<dim3(128, 32, 1), 256, 0, stream>>>(fc1w, fc1t, nullptr, 2048, 8192);
  k_tcvt<false><<<dim3(32, 128, 1), 256, 0, stream>>>(fc2w, fc2t, nullptr, 8192, 2048);

  // V^T = wvt @ xh^T  (8-phase, split-K=4) -> combine to bf16
  k_gemm8<0><<<dim3(8, 8, 4), 512, 0, stream>>>(
      wvt, xh, vtp, nullptr, nullptr, 2048, 2048, 2048, 4);
  k_combine4<<<4096, 256, 0, stream>>>(vtp, PSTR, vtb);
  // fused Q,K projection (8-phase split-precision), 1/sqrt(128) on Q cols
  k_split8<<<dim3(16, 16), 512, 0, stream>>>(
      xh, xl, qk_bh, qk_bl, qkh, qkl, 2048, 4096, 2048,
      0.08838834764831845f, 2048);
  // attention -> concat
  k_flash<<<dim3(32, 16), 256, 0, stream>>>(qkh, qkl, qkh + 2048, qkl + 2048,
                                            vtb, cc);
  // out projection (8-phase, split-K=4)
  k_gemm8<0><<<dim3(8, 8, 4), 512, 0, stream>>>(
      cc, wpt, aop, nullptr, nullptr, 2048, 2048, 2048, 4);
  // h = LN(x + sum aop)
  k_add_ln<<<2048, 256, 0, stream>>>(x, aop, PSTR, 4, nullptr, g1, b1, h32, hbf);
  // ff1 = relu(h @ fc1 + b1)
  k_gemm8<2><<<dim3(32, 8, 1), 512, 0, stream>>>(
      hbf, fc1t, nullptr, ff1, fc1b, 2048, 8192, 2048, 1);
  // ff2 partials (8-phase, split-K=4 over K=8192)
  k_gemm8<0><<<dim3(8, 8, 4), 512, 0, stream>>>(
      ff1, fc2t, ffp, nullptr, nullptr, 2048, 2048, 8192, 4);
  // out = LN(h + sum ffp + fc2b)
  k_add_ln<<<2048, 256, 0, stream>>>(h32, ffp, PSTR, 4, fc2b, g2, b2, out, nullptr);
}

// Round 12
// 524.614 us; speedup vs baseline: 1.0502x; 1.0502x over previous
//
#include <hip/hip_runtime.h>

// TransformerBlock fused pipeline for MI355X (gfx950).
// SEQ=2048, D_MODEL=2048, H=16, DK=DV=128, DFF=8192. fp32 in/out.
//
// R12: flash reverted to the proven R2/R9 body (KVBLK=64, cp16 staging,
// syncthreads schedule -- R11's KVBLK=32 counted-vmcnt halved MFMA per
// softmax round and lost). Changes: dedicated P (56KB, no post-QK barrier)
// + T13 defer-max (skip rescale when __all(mx<=mo+8); exact normalization).
// T1 bijective XCD swizzle on gemm8/split8 blockIdx. Rest R9-exact.

typedef __bf16 bf16;
typedef __attribute__((ext_vector_type(8))) __bf16 bf16x8;
typedef __attribute__((ext_vector_type(4))) __bf16 bf16x4;
typedef __attribute__((ext_vector_type(4))) float f32x4;

#define MFMA(a, b, c) __builtin_amdgcn_mfma_f32_16x16x32_bf16((a), (b), (c), 0, 0, 0)
#define NEG_INF (-3.402823466e38f)

__device__ __forceinline__ void cp16(void* lds, const void* g) {
  __builtin_amdgcn_global_load_lds(
      (const __attribute__((address_space(1))) unsigned int*)g,
      (__attribute__((address_space(3))) unsigned int*)lds, 16, 0, 0);
}

#define SBAR() __builtin_amdgcn_sched_barrier(0)
#define GBAR()                              \
  do {                                      \
    asm volatile("" ::: "memory");          \
    __builtin_amdgcn_s_barrier();           \
    asm volatile("" ::: "memory");          \
  } while (0)
#define LGKM0()                                         \
  do {                                                  \
    asm volatile("s_waitcnt lgkmcnt(0)" ::: "memory");  \
    __builtin_amdgcn_sched_barrier(0);                  \
  } while (0)
#define VMC6()                                          \
  do {                                                  \
    asm volatile("s_waitcnt vmcnt(6)" ::: "memory");    \
    __builtin_amdgcn_sched_barrier(0);                  \
  } while (0)

// bijective XCD swizzle for 2D grids with (gx*gy)%8==0 (T1, m204 variant)
__device__ __forceinline__ void xcd_swz(int& bx, int& by) {
  const int gx = gridDim.x, nwg = gx * gridDim.y;
  const int lid = by * gx + bx;
  const int swz = (lid & 7) * (nwg >> 3) + (lid >> 3);
  bx = swz % gx;
  by = swz / gx;
}

// ---------------- converts ----------------

__global__ void k_split_x(const float* __restrict__ x, bf16* __restrict__ xh,
                          bf16* __restrict__ xl) {
  int i = blockIdx.x * 256 + threadIdx.x;
  f32x4 v = ((const f32x4*)x)[i];
  bf16x4 h, l;
#pragma unroll
  for (int j = 0; j < 4; ++j) {
    bf16 hi = (bf16)v[j];
    h[j] = hi;
    l[j] = (bf16)(v[j] - (float)hi);
  }
  ((bf16x4*)xh)[i] = h;
  ((bf16x4*)xl)[i] = l;
}

template <bool SPLIT>
__global__ void k_tcvt(const float* __restrict__ in, bf16* __restrict__ oh,
                       bf16* __restrict__ ol, int R, int C) {
  __shared__ float t[64][65];
  long zoff = (long)blockIdx.z * R * C;
  int c0 = blockIdx.x * 64, r0 = blockIdx.y * 64;
  int cc = threadIdx.x & 63, rr = threadIdx.x >> 6;
#pragma unroll
  for (int i = 0; i < 16; ++i) {
    int r = i * 4 + rr;
    t[r][cc] = in[zoff + (long)(r0 + r) * C + c0 + cc];
  }
  __syncthreads();
#pragma unroll
  for (int i = 0; i < 16; ++i) {
    int orow = i * 4 + rr;
    float v = t[cc][orow];
    long oidx = zoff + (long)(c0 + orow) * R + r0 + cc;
    bf16 hi = (bf16)v;
    oh[oidx] = hi;
    if (SPLIT) ol[oidx] = (bf16)(v - (float)hi);
  }
}

// combine 4 fp32 partials -> bf16
__global__ void k_combine4(const float* __restrict__ p, long pstr,
                           bf16* __restrict__ o) {
  int i = blockIdx.x * 256 + threadIdx.x;
  f32x4 v = ((const f32x4*)p)[i];
#pragma unroll
  for (int zz = 1; zz < 4; ++zz) v += ((const f32x4*)(p + zz * pstr))[i];
  bf16x4 ob;
#pragma unroll
  for (int j = 0; j < 4; ++j) ob[j] = (bf16)v[j];
  ((bf16x4*)o)[i] = ob;
}

// ---------------- 8-phase 256^2 GEMM (R6 value-verified) + XCD swizzle -----
template <int EPI>
__global__ __launch_bounds__(512, 1) void k_gemm8(
    const bf16* __restrict__ A, const bf16* __restrict__ B,
    float* __restrict__ Cf, bf16* __restrict__ Cb,
    const float* __restrict__ bias, int M, int N, int K, int nsplit) {
  __shared__ char lds[131072];
  const int tid = threadIdx.x, w = tid >> 6, l = tid & 63;
  const int l16 = l & 15, lg = l >> 4;
  const int wr = w >> 2, wc = w & 3;
  int bx = blockIdx.x, by = blockIdx.y;
  xcd_swz(bx, by);
  const long bm0 = (long)by * 256, bn0 = (long)bx * 256;
  const int z = blockIdx.z;
  const int ksz = K / nsplit, kbeg = z * ksz;
  const int nt = ksz >> 6;
  const long lK = K;

  const int srow = w * 8 + (l >> 3);
  const int sslot = (l & 7) ^ (l >> 3);

  auto STAGE = [&](int bufp, int isB, int h, int tt) {
    int tc = tt < nt ? tt : nt - 1;
    char* dst = lds + bufp * 65536 + isB * 32768 + h * 16384 + w * 1024;
    const bf16* G = isB ? B : A;
    long r0 = (isB ? bn0 : bm0) + h * 128 + srow;
    const bf16* src = G + r0 * lK + kbeg + tc * 64 + sslot * 8;
    cp16(dst, src);
    cp16(dst + 8192, src + 64 * lK);
  };
  auto LDA = [&](int bufp, int mf, int ks) -> bf16x8 {
    int inrow = (mf & 3) * 32 + wr * 16 + l16;
    int byo = bufp * 65536 + (mf >> 2) * 16384 + inrow * 128 +
              ((((ks << 2) + lg) ^ (inrow & 7)) << 4);
    return *(const bf16x8*)(lds + byo);
  };
  auto LDB = [&](int bufp, int nf, int ks) -> bf16x8 {
    int inrow = (nf & 1) * 64 + wc * 16 + l16;
    int byo = bufp * 65536 + 32768 + (nf >> 1) * 16384 + inrow * 128 +
              ((((ks << 2) + lg) ^ (inrow & 7)) << 4);
    return *(const bf16x8*)(lds + byo);
  };

  f32x4 acc[8][4];
#pragma unroll
  for (int mf = 0; mf < 8; ++mf)
#pragma unroll
    for (int nf = 0; nf < 4; ++nf)
#pragma unroll
      for (int j = 0; j < 4; ++j) acc[mf][nf][j] = 0.f;

  STAGE(0, 0, 0, 0);
  STAGE(0, 1, 0, 0);
  STAGE(0, 0, 1, 0);
  STAGE(0, 1, 1, 0);
  STAGE(1, 1, 0, 1);
  STAGE(1, 0, 1, 1);
  STAGE(1, 1, 1, 1);
  SBAR();
  VMC6();
  GBAR();

  bf16x8 a[4][2], b[2][2];
  for (int t = 0; t < nt; ++t) {
    const int cb = t & 1, nb = cb ^ 1;
#pragma unroll
    for (int mf = 0; mf < 4; ++mf)
#pragma unroll
      for (int ks = 0; ks < 2; ++ks) a[mf][ks] = LDA(cb, mf, ks);
#pragma unroll
    for (int nf = 0; nf < 2; ++nf)
#pragma unroll
      for (int ks = 0; ks < 2; ++ks) b[nf][ks] = LDB(cb, nf, ks);
    STAGE(nb, 0, 0, t + 1);
    SBAR();
    GBAR();
    LGKM0();
    __builtin_amdgcn_s_setprio(1);
#pragma unroll
    for (int mf = 0; mf < 4; ++mf)
#pragma unroll
      for (int nf = 0; nf < 2; ++nf)
#pragma unroll
        for (int ks = 0; ks < 2; ++ks)
          acc[mf][nf] = MFMA(a[mf][ks], b[nf][ks], acc[mf][nf]);
    __builtin_amdgcn_s_setprio(0);
    GBAR();
#pragma unroll
    for (int mf = 0; mf < 4; ++mf)
#pragma unroll
      for (int ks = 0; ks < 2; ++ks) a[mf][ks] = LDA(cb, mf + 4, ks);
    STAGE(cb, 1, 0, t + 2);
    SBAR();
    GBAR();
    LGKM0();
    __builtin_amdgcn_s_setprio(1);
#pragma unroll
    for (int mf = 0; mf < 4; ++mf)
#pragma unroll
      for (int nf = 0; nf < 2; ++nf)
#pragma unroll
        for (int ks = 0; ks < 2; ++ks)
          acc[mf + 4][nf] = MFMA(a[mf][ks], b[nf][ks], acc[mf + 4][nf]);
    __builtin_amdgcn_s_setprio(0);
    GBAR();
#pragma unroll
    for (int nf = 0; nf < 2; ++nf)
#pragma unroll
      for (int ks = 0; ks < 2; ++ks) b[nf][ks] = LDB(cb, nf + 2, ks);
    GBAR();
    LGKM0();
    __builtin_amdgcn_s_setprio(1);
#pragma unroll
    for (int mf = 0; mf < 4; ++mf)
#pragma unroll
      for (int nf = 0; nf < 2; ++nf)
#pragma unroll
        for (int ks = 0; ks < 2; ++ks)
          acc[mf + 4][nf + 2] = MFMA(a[mf][ks], b[nf][ks], acc[mf + 4][nf + 2]);
    __builtin_amdgcn_s_setprio(0);
    GBAR();
#pragma unroll
    for (int mf = 0; mf < 4; ++mf)
#pragma unroll
      for (int ks = 0; ks < 2; ++ks) a[mf][ks] = LDA(cb, mf, ks);
    STAGE(cb, 0, 1, t + 2);
    STAGE(cb, 1, 1, t + 2);
    SBAR();
    VMC6();
    GBAR();
    LGKM0();
    __builtin_amdgcn_s_setprio(1);
#pragma unroll
    for (int mf = 0; mf < 4; ++mf)
#pragma unroll
      for (int nf = 0; nf < 2; ++nf)
#pragma unroll
        for (int ks = 0; ks < 2; ++ks)
          acc[mf][nf + 2] = MFMA(a[mf][ks], b[nf][ks], acc[mf][nf + 2]);
    __builtin_amdgcn_s_setprio(0);
    GBAR();
  }
  asm volatile("s_waitcnt vmcnt(0) lgkmcnt(0)" ::: "memory");

#pragma unroll
  for (int mf = 0; mf < 8; ++mf)
#pragma unroll
    for (int nf = 0; nf < 4; ++nf) {
      long col = bn0 + nf * 64 + wc * 16 + l16;
      float bv = (EPI == 2) ? bias[col] : 0.f;
#pragma unroll
      for (int jj = 0; jj < 4; ++jj) {
        long row = bm0 + mf * 32 + wr * 16 + lg * 4 + jj;
        float v = acc[mf][nf][jj];
        if (EPI == 0) {
          Cf[(long)z * M * N + row * N + col] = v;
        } else {
          v = fmaxf(v + bv, 0.f);
          Cb[row * N + col] = (bf16)v;
        }
      }
    }
}

// ---------------- 8-phase split-precision GEMM (QK proj) + XCD swizzle -----
__global__ __launch_bounds__(512, 1) void k_split8(
    const bf16* __restrict__ Ah_g, const bf16* __restrict__ Al_g,
    const bf16* __restrict__ Bh_g, const bf16* __restrict__ Bl_g,
    bf16* __restrict__ Ch, bf16* __restrict__ Cl,
    int M, int N, int K, float scale, int scale_ncols) {
  __shared__ char lds[98304];
  const int tid = threadIdx.x, w = tid >> 6, l = tid & 63;
  const int l16 = l & 15, lg = l >> 4;
  const int wr = w >> 2, wc = w & 3;
  int bx = blockIdx.x, by = blockIdx.y;
  xcd_swz(bx, by);
  const long bm0 = (long)by * 128, bn0 = (long)bx * 256;
  const int nt = K >> 5;
  const long lK = K;

  const int srcrow = tid >> 2;
  const int ss = (tid & 3) ^ ((tid >> 3) & 3);

  auto STG_A = [&](int bufp, int isLo, int tt) {
    int tc = tt < nt ? tt : nt - 1;
    char* dst = lds + bufp * 49152 + isLo * 8192 + tid * 16;
    const bf16* G = isLo ? Al_g : Ah_g;
    cp16(dst, &G[(bm0 + srcrow) * lK + tc * 32 + ss * 8]);
  };
  auto STG_B = [&](int bufp, int isLo, int half, int tt) {
    int tc = tt < nt ? tt : nt - 1;
    char* dst = lds + bufp * 49152 + 16384 + isLo * 16384 + half * 8192 + tid * 16;
    const bf16* G = isLo ? Bl_g : Bh_g;
    cp16(dst, &G[(bn0 + half * 128 + srcrow) * lK + tc * 32 + ss * 8]);
  };
  auto LDA8 = [&](int bufp, int mf, int isLo) -> bf16x8 {
    int row = mf * 32 + wr * 16 + l16;
    int byo = bufp * 49152 + isLo * 8192 + row * 64 +
              ((lg ^ ((row >> 1) & 3)) << 4);
    return *(const bf16x8*)(lds + byo);
  };
  auto LDB8 = [&](int bufp, int nf, int isLo) -> bf16x8 {
    int row = nf * 64 + wc * 16 + l16;
    int byo = bufp * 49152 + 16384 + isLo * 16384 + row * 64 +
              ((lg ^ ((row >> 1) & 3)) << 4);
    return *(const bf16x8*)(lds + byo);
  };

  f32x4 acc[4][4];
#pragma unroll
  for (int mf = 0; mf < 4; ++mf)
#pragma unroll
    for (int nf = 0; nf < 4; ++nf)
#pragma unroll
      for (int j = 0; j < 4; ++j) acc[mf][nf][j] = 0.f;

  STG_B(0, 0, 0, 0); STG_B(0, 1, 0, 0);
  STG_A(0, 0, 0);    STG_A(0, 1, 0);
  STG_B(0, 0, 1, 0); STG_B(0, 1, 1, 0);
  STG_B(1, 0, 0, 1); STG_B(1, 1, 0, 1);
  STG_A(1, 0, 1);    STG_A(1, 1, 1);
  STG_B(1, 0, 1, 1); STG_B(1, 1, 1, 1);
  SBAR();
  VMC6();
  GBAR();

  bf16x8 ah[4], al[4], bh[2], bl[2];
  for (int t = 0; t < nt; ++t) {
    const int cb = t & 1;
    // P1
#pragma unroll
    for (int mf = 0; mf < 2; ++mf) {
      ah[mf] = LDA8(cb, mf, 0);
      al[mf] = LDA8(cb, mf, 1);
    }
#pragma unroll
    for (int nf = 0; nf < 2; ++nf) {
      bh[nf] = LDB8(cb, nf, 0);
      bl[nf] = LDB8(cb, nf, 1);
    }
    SBAR();
    GBAR();
    LGKM0();
    __builtin_amdgcn_s_setprio(1);
#pragma unroll
    for (int mf = 0; mf < 2; ++mf)
#pragma unroll
      for (int nf = 0; nf < 2; ++nf) {
        acc[mf][nf] = MFMA(ah[mf], bh[nf], acc[mf][nf]);
        acc[mf][nf] = MFMA(ah[mf], bl[nf], acc[mf][nf]);
        acc[mf][nf] = MFMA(al[mf], bh[nf], acc[mf][nf]);
      }
    __builtin_amdgcn_s_setprio(0);
    GBAR();
    // P2
#pragma unroll
    for (int mf = 2; mf < 4; ++mf) {
      ah[mf] = LDA8(cb, mf, 0);
      al[mf] = LDA8(cb, mf, 1);
    }
    STG_B(cb, 0, 0, t + 2);
    STG_B(cb, 1, 0, t + 2);
    SBAR();
    GBAR();
    LGKM0();
    __builtin_amdgcn_s_setprio(1);
#pragma unroll
    for (int mf = 2; mf < 4; ++mf)
#pragma unroll
      for (int nf = 0; nf < 2; ++nf) {
        acc[mf][nf] = MFMA(ah[mf], bh[nf], acc[mf][nf]);
        acc[mf][nf] = MFMA(ah[mf], bl[nf], acc[mf][nf]);
        acc[mf][nf] = MFMA(al[mf], bh[nf], acc[mf][nf]);
      }
    __builtin_amdgcn_s_setprio(0);
    GBAR();
    // P3
#pragma unroll
    for (int nf = 0; nf < 2; ++nf) {
      bh[nf] = LDB8(cb, nf + 2, 0);
      bl[nf] = LDB8(cb, nf + 2, 1);
    }
    STG_A(cb, 0, t + 2);
    STG_A(cb, 1, t + 2);
    SBAR();
    GBAR();
    LGKM0();
    __builtin_amdgcn_s_setprio(1);
#pragma unroll
    for (int mf = 2; mf < 4; ++mf)
#pragma unroll
      for (int nf = 0; nf < 2; ++nf) {
        acc[mf][nf + 2] = MFMA(ah[mf], bh[nf], acc[mf][nf + 2]);
        acc[mf][nf + 2] = MFMA(ah[mf], bl[nf], acc[mf][nf + 2]);
        acc[mf][nf + 2] = MFMA(al[mf], bh[nf], acc[mf][nf + 2]);
      }
    __builtin_amdgcn_s_setprio(0);
    GBAR();
    // P4
    STG_B(cb, 0, 1, t + 2);
    STG_B(cb, 1, 1, t + 2);
    SBAR();
    VMC6();
    GBAR();
    __builtin_amdgcn_s_setprio(1);
#pragma unroll
    for (int mf = 0; mf < 2; ++mf)
#pragma unroll
      for (int nf = 0; nf < 2; ++nf) {
        acc[mf][nf + 2] = MFMA(ah[mf], bh[nf], acc[mf][nf + 2]);
        acc[mf][nf + 2] = MFMA(ah[mf], bl[nf], acc[mf][nf + 2]);
        acc[mf][nf + 2] = MFMA(al[mf], bh[nf], acc[mf][nf + 2]);
      }
    __builtin_amdgcn_s_setprio(0);
    GBAR();
  }
  asm volatile("s_waitcnt vmcnt(0) lgkmcnt(0)" ::: "memory");

#pragma unroll
  for (int mf = 0; mf < 4; ++mf)
#pragma unroll
    for (int nf = 0; nf < 4; ++nf) {
      long col = bn0 + nf * 64 + wc * 16 + l16;
      float sc = (col < scale_ncols) ? scale : 1.0f;
#pragma unroll
      for (int j = 0; j < 4; ++j) {
        long row = bm0 + mf * 32 + wr * 16 + lg * 4 + j;
        float v = acc[mf][nf][j] * sc;
        bf16 hi = (bf16)v;
        Ch[row * N + col] = hi;
        Cl[row * N + col] = (bf16)(v - (float)hi);
      }
    }
}

// ---------------- flash attention (R2 body + dedicated P + defer-max) ------
__global__ __launch_bounds__(256, 2) void k_flash(
    const bf16* __restrict__ Qh, const bf16* __restrict__ Ql,
    const bf16* __restrict__ Kh, const bf16* __restrict__ Kl,
    const bf16* __restrict__ Vt, bf16* __restrict__ Oc) {
  __shared__ bf16 sm[28672];  // 56KB: Kh[64][128] Kl[64][128] Vt[128][64] P[64][64]
  bf16* sKh = sm;
  bf16* sKl = sm + 8192;
  bf16* sVt = sm + 16384;
  bf16* sP = sm + 24576;
  const int tid = threadIdx.x, w = tid >> 6, l = tid & 63;
  const int l16 = l & 15, lg = l >> 4;
  const int head = blockIdx.y;
  const long q0 = (long)blockIdx.x * 64;

  bf16x8 qh_r[4], ql_r[4];
#pragma unroll
  for (int kk = 0; kk < 4; ++kk) {
    long off = (q0 + w * 16 + l16) * 4096 + head * 128 + kk * 32 + lg * 8;
    qh_r[kk] = *(const bf16x8*)&Qh[off];
    ql_r[kk] = *(const bf16x8*)&Ql[off];
  }

  f32x4 acc_o[8];
#pragma unroll
  for (int n = 0; n < 8; ++n)
#pragma unroll
    for (int j = 0; j < 4; ++j) acc_o[n][j] = 0.f;
  float mrow[4], lrow[4];
#pragma unroll
  for (int j = 0; j < 4; ++j) {
    mrow[j] = NEG_INF;
    lrow[j] = 0.f;
  }

  for (int t0 = 0; t0 < 2048; t0 += 64) {
    __syncthreads();
#pragma unroll
    for (int i = 0; i < 4; ++i) {
      int c = (w * 4 + i) * 64 + l;
      int rk = c >> 4, sk = (c & 15) ^ (rk & 7);
      long ko = (long)(t0 + rk) * 4096 + head * 128 + sk * 8;
      int db = (w * 4 + i) * 512;
      cp16(&sKh[db], &Kh[ko]);
      cp16(&sKl[db], &Kl[ko]);
      int rv = c >> 3, sv = (c & 7) ^ (rv & 7);
      long vo = (long)(head * 128 + rv) * 2048 + t0 + sv * 8;
      cp16(&sVt[db], &Vt[vo]);
    }
    __syncthreads();

    f32x4 s[4];
#pragma unroll
    for (int n = 0; n < 4; ++n)
#pragma unroll
      for (int j = 0; j < 4; ++j) s[n][j] = 0.f;
    __builtin_amdgcn_s_setprio(1);
#pragma unroll
    for (int kk = 0; kk < 4; ++kk) {
      bf16x8 bh[4], bl[4];
#pragma unroll
      for (int n = 0; n < 4; ++n) {
        int r = n * 16 + l16;
        int byo = r * 256 + (((kk * 4 + lg) ^ (r & 7)) << 4);
        bh[n] = *(const bf16x8*)((const char*)sKh + byo);
        bl[n] = *(const bf16x8*)((const char*)sKl + byo);
      }
#pragma unroll
      for (int n = 0; n < 4; ++n) {
        s[n] = MFMA(qh_r[kk], bh[n], s[n]);
        s[n] = MFMA(qh_r[kk], bl[n], s[n]);
        s[n] = MFMA(ql_r[kk], bh[n], s[n]);
      }
    }
    __builtin_amdgcn_s_setprio(0);

    // online softmax with T13 defer-max (P rows per-wave; no barrier needed)
#pragma unroll
    for (int j = 0; j < 4; ++j) {
      float mx = fmaxf(fmaxf(s[0][j], s[1][j]), fmaxf(s[2][j], s[3][j]));
      mx = fmaxf(mx, __shfl_xor(mx, 1));
      mx = fmaxf(mx, __shfl_xor(mx, 2));
      mx = fmaxf(mx, __shfl_xor(mx, 4));
      mx = fmaxf(mx, __shfl_xor(mx, 8));
      float mo = mrow[j];
      float f = 1.f;
      const bool upd = (__all(mx <= mo + 8.f) == 0);
      if (upd) {
        float mn = fmaxf(mo, mx);
        f = __expf(mo - mn);
        mrow[j] = mn;
        mo = mn;
      }
      int prow = w * 16 + lg * 4 + j;
      float ssum = 0.f;
#pragma unroll
      for (int n = 0; n < 4; ++n) {
        float p = __expf(s[n][j] - mo);
        ssum += p;
        int byo = prow * 128 + (((n * 16 + l16) * 2) ^ ((prow & 7) << 4));
        *(bf16*)((char*)sP + byo) = (bf16)p;
      }
      ssum += __shfl_xor(ssum, 1);
      ssum += __shfl_xor(ssum, 2);
      ssum += __shfl_xor(ssum, 4);
      ssum += __shfl_xor(ssum, 8);
      lrow[j] = lrow[j] * f + ssum;
      if (upd) {
#pragma unroll
        for (int n = 0; n < 8; ++n) acc_o[n][j] *= f;
      }
    }

    __builtin_amdgcn_s_setprio(1);
#pragma unroll
    for (int kk = 0; kk < 2; ++kk) {
      bf16x8 pa, bv[8];
      {
        int r = w * 16 + l16;
        int byo = r * 128 + (((kk * 4 + lg) ^ (r & 7)) << 4);
        pa = *(const bf16x8*)((const char*)sP + byo);
      }
#pragma unroll
      for (int n = 0; n < 8; ++n) {
        int r = n * 16 + l16;
        int byo = r * 128 + (((kk * 4 + lg) ^ (r & 7)) << 4);
        bv[n] = *(const bf16x8*)((const char*)sVt + byo);
      }
#pragma unroll
      for (int n = 0; n < 8; ++n) acc_o[n] = MFMA(pa, bv[n], acc_o[n]);
    }
    __builtin_amdgcn_s_setprio(0);
  }

#pragma unroll
  for (int j = 0; j < 4; ++j) {
    float rinv = 1.f / lrow[j];
    long row = q0 + w * 16 + lg * 4 + j;
#pragma unroll
    for (int n = 0; n < 8; ++n)
      Oc[row * 2048 + head * 128 + n * 16 + l16] = (bf16)(acc_o[n][j] * rinv);
  }
}

// ---------------- residual + np partials + LayerNorm ----------------
__global__ __launch_bounds__(256) void k_add_ln(
    const float* __restrict__ a, const float* __restrict__ p, long pstr,
    int np, const float* __restrict__ bias, const float* __restrict__ g,
    const float* __restrict__ be, float* __restrict__ o32,
    bf16* __restrict__ obf) {
  __shared__ float red[8];
  int row = blockIdx.x, tid = threadIdx.x;
  const float* pa = a + (long)row * 2048;
  f32x4 v[2];
  float sum = 0.f, sq = 0.f;
#pragma unroll
  for (int i = 0; i < 2; ++i) {
    int idx = i * 1024 + tid * 4;
    v[i] = *(const f32x4*)(pa + idx);
    for (int zz = 0; zz < np; ++zz)
      v[i] += *(const f32x4*)(p + zz * pstr + (long)row * 2048 + idx);
    if (bias != nullptr) v[i] += *(const f32x4*)(bias + idx);
#pragma unroll
    for (int j = 0; j < 4; ++j) {
      sum += v[i][j];
      sq += v[i][j] * v[i][j];
    }
  }
#pragma unroll
  for (int o = 1; o < 64; o <<= 1) {
    sum += __shfl_xor(sum, o);
    sq += __shfl_xor(sq, o);
  }
  int w = tid >> 6;
  if ((tid & 63) == 0) {
    red[w * 2] = sum;
    red[w * 2 + 1] = sq;
  }
  __syncthreads();
  sum = red[0] + red[2] + red[4] + red[6];
  sq = red[1] + red[3] + red[5] + red[7];
  float mu = sum * (1.f / 2048.f);
  float var = sq * (1.f / 2048.f) - mu * mu;
  float rs = rsqrtf(var + 1e-5f);
#pragma unroll
  for (int i = 0; i < 2; ++i) {
    int idx = i * 1024 + tid * 4;
    f32x4 vg = *(const f32x4*)(g + idx);
    f32x4 vb = *(const f32x4*)(be + idx);
    f32x4 o;
#pragma unroll
    for (int j = 0; j < 4; ++j) o[j] = (v[i][j] - mu) * rs * vg[j] + vb[j];
    *(f32x4*)(o32 + (long)row * 2048 + idx) = o;
    if (obf != nullptr) {
      bf16x4 ob;
#pragma unroll
      for (int j = 0; j < 4; ++j) ob[j] = (bf16)o[j];
      *(bf16x4*)(obf + (long)row * 2048 + idx) = ob;
    }
  }
}

// ---------------- launch ----------------
extern "C" void kernel_launch(void* const* d_in, const int* in_sizes, int n_in,
                              void* d_out, int out_size, void* d_ws, size_t ws_size,
                              hipStream_t stream) {
  const float* x    = (const float*)d_in[0];
  const float* wq   = (const float*)d_in[1];
  const float* wk   = (const float*)d_in[2];
  const float* wv   = (const float*)d_in[3];
  const float* wp   = (const float*)d_in[4];
  const float* g1   = (const float*)d_in[5];
  const float* b1   = (const float*)d_in[6];
  const float* fc1w = (const float*)d_in[7];
  const float* fc1b = (const float*)d_in[8];
  const float* fc2w = (const float*)d_in[9];
  const float* fc2b = (const float*)d_in[10];
  const float* g2   = (const float*)d_in[11];
  const float* b2   = (const float*)d_in[12];
  float* out = (float*)d_out;

  char* ws = (char*)d_ws;
  const size_t MB = 1024 * 1024;
  if (ws_size < 216 * MB) return;
  const long W4M = 4L * 1024 * 1024;

  // ADJACENCY CONSTRAINT: qk_bh = [wq^T | wk^T] hi as ONE [4096][2048];
  // qk_bl likewise lo (split8's B operands span both).
  bf16* xh    = (bf16*)(ws + 0 * MB);
  bf16* xl    = (bf16*)(ws + 8 * MB);
  bf16* qk_bh = (bf16*)(ws + 16 * MB);   // 16MB
  bf16* qk_bl = (bf16*)(ws + 32 * MB);   // 16MB
  bf16* wvt   = (bf16*)(ws + 48 * MB);
  bf16* wpt   = (bf16*)(ws + 56 * MB);
  bf16* fc1t  = (bf16*)(ws + 64 * MB);   // 32MB
  bf16* fc2t  = (bf16*)(ws + 96 * MB);   // 32MB
  float* vtp  = (float*)(ws + 128 * MB); // 4x16MB vt partials
  bf16* vtb   = (bf16*)(ws + 192 * MB);  // 8MB
  bf16* qkh   = (bf16*)(ws + 128 * MB);  // 16MB (vtp dead)
  bf16* qkl   = (bf16*)(ws + 144 * MB);  // 16MB
  bf16* cc    = (bf16*)(ws + 200 * MB);  // 8MB concat
  float* aop  = (float*)(ws + 128 * MB); // 4x16MB (qk dead post-flash)
  float* h32  = (float*)(ws + 192 * MB); // 16MB (vtb dead post-flash)
  bf16*  hbf  = (bf16*)(ws + 208 * MB);  // 8MB
  bf16*  ff1  = (bf16*)(ws + 128 * MB);  // 32MB (aop dead after LN1)
  float* ffp  = (float*)(ws + 0 * MB);   // 4x16MB (x/qk_b dead)
  const long PSTR = 4194304L;

  // converts
  k_split_x<<<4096, 256, 0, stream>>>(x, xh, xl);
  k_tcvt<true ><<<dim3(2, 32, 16), 256, 0, stream>>>(wq, qk_bh, qk_bl, 2048, 128);
  k_tcvt<true ><<<dim3(2, 32, 16), 256, 0, stream>>>(wk, qk_bh + W4M, qk_bl + W4M,
                                                     2048, 128);
  k_tcvt<false><<<dim3(2, 32, 16), 256, 0, stream>>>(wv, wvt, nullptr, 2048, 128);
  k_tcvt<false><<<dim3(32, 32, 1), 256, 0, stream>>>(wp, wpt, nullptr, 2048, 2048);
  k_tcvt<false><<<dim3(128, 32, 1), 256, 0, stream>>>(fc1w, fc1t, nullptr, 2048, 8192);
  k_tcvt<false><<<dim3(32, 128, 1), 256, 0, stream>>>(fc2w, fc2t, nullptr, 8192, 2048);

  // V^T = wvt @ xh^T  (8-phase, split-K=4) -> combine to bf16
  k_gemm8<0><<<dim3(8, 8, 4), 512, 0, stream>>>(
      wvt, xh, vtp, nullptr, nullptr, 2048, 2048, 2048, 4);
  k_combine4<<<4096, 256, 0, stream>>>(vtp, PSTR, vtb);
  // fused Q,K projection (8-phase split-precision), 1/sqrt(128) on Q cols
  k_split8<<<dim3(16, 16), 512, 0, stream>>>(
      xh, xl, qk_bh, qk_bl, qkh, qkl, 2048, 4096, 2048,
      0.08838834764831845f, 2048);
  // attention -> concat
  k_flash<<<dim3(32, 16), 256, 0, stream>>>(qkh, qkl, qkh + 2048, qkl + 2048,
                                            vtb, cc);
  // out projection (8-phase, split-K=4)
  k_gemm8<0><<<dim3(8, 8, 4), 512, 0, stream>>>(
      cc, wpt, aop, nullptr, nullptr, 2048, 2048, 2048, 4);
  // h = LN(x + sum aop)
  k_add_ln<<<2048, 256, 0, stream>>>(x, aop, PSTR, 4, nullptr, g1, b1, h32, hbf);
  // ff1 = relu(h @ fc1 + b1)
  k_gemm8<2><<<dim3(32, 8, 1), 512, 0, stream>>>(
      hbf, fc1t, nullptr, ff1, fc1b, 2048, 8192, 2048, 1);
  // ff2 partials (8-phase, split-K=4 over K=8192)
  k_gemm8<0><<<dim3(8, 8, 4), 512, 0, stream>>>(
      ff1, fc2t, ffp, nullptr, nullptr, 2048, 2048, 8192, 4);
  // out = LN(h + sum ffp + fc2b)
  k_add_ln<<<2048, 256, 0, stream>>>(h32, ffp, PSTR, 4, fc2b, g2, b2, out, nullptr);
}

// Round 13
// 518.461 us; speedup vs baseline: 1.0627x; 1.0119x over previous
//
#include <hip/hip_runtime.h>

// TransformerBlock fused pipeline for MI355X (gfx950).
// SEQ=2048, D_MODEL=2048, H=16, DK=DV=128, DFF=8192. fp32 in/out.
//
// R13: consolidation at best-known. Flash = R9-exact body (aliased P, post-QK
// barrier, plain online softmax -- 121us; R12's defer-max cost +14us and is
// dropped). gemm8/split8 keep R12's bijective XCD swizzle (~5us net gain).

typedef __bf16 bf16;
typedef __attribute__((ext_vector_type(8))) __bf16 bf16x8;
typedef __attribute__((ext_vector_type(4))) __bf16 bf16x4;
typedef __attribute__((ext_vector_type(4))) float f32x4;

#define MFMA(a, b, c) __builtin_amdgcn_mfma_f32_16x16x32_bf16((a), (b), (c), 0, 0, 0)
#define NEG_INF (-3.402823466e38f)

__device__ __forceinline__ void cp16(void* lds, const void* g) {
  __builtin_amdgcn_global_load_lds(
      (const __attribute__((address_space(1))) unsigned int*)g,
      (__attribute__((address_space(3))) unsigned int*)lds, 16, 0, 0);
}

#define SBAR() __builtin_amdgcn_sched_barrier(0)
#define GBAR()                              \
  do {                                      \
    asm volatile("" ::: "memory");          \
    __builtin_amdgcn_s_barrier();           \
    asm volatile("" ::: "memory");          \
  } while (0)
#define LGKM0()                                         \
  do {                                                  \
    asm volatile("s_waitcnt lgkmcnt(0)" ::: "memory");  \
    __builtin_amdgcn_sched_barrier(0);                  \
  } while (0)
#define VMC6()                                          \
  do {                                                  \
    asm volatile("s_waitcnt vmcnt(6)" ::: "memory");    \
    __builtin_amdgcn_sched_barrier(0);                  \
  } while (0)

// bijective XCD swizzle for 2D grids with (gx*gy)%8==0 (T1, m204 variant)
__device__ __forceinline__ void xcd_swz(int& bx, int& by) {
  const int gx = gridDim.x, nwg = gx * gridDim.y;
  const int lid = by * gx + bx;
  const int swz = (lid & 7) * (nwg >> 3) + (lid >> 3);
  bx = swz % gx;
  by = swz / gx;
}

// ---------------- converts ----------------

__global__ void k_split_x(const float* __restrict__ x, bf16* __restrict__ xh,
                          bf16* __restrict__ xl) {
  int i = blockIdx.x * 256 + threadIdx.x;
  f32x4 v = ((const f32x4*)x)[i];
  bf16x4 h, l;
#pragma unroll
  for (int j = 0; j < 4; ++j) {
    bf16 hi = (bf16)v[j];
    h[j] = hi;
    l[j] = (bf16)(v[j] - (float)hi);
  }
  ((bf16x4*)xh)[i] = h;
  ((bf16x4*)xl)[i] = l;
}

template <bool SPLIT>
__global__ void k_tcvt(const float* __restrict__ in, bf16* __restrict__ oh,
                       bf16* __restrict__ ol, int R, int C) {
  __shared__ float t[64][65];
  long zoff = (long)blockIdx.z * R * C;
  int c0 = blockIdx.x * 64, r0 = blockIdx.y * 64;
  int cc = threadIdx.x & 63, rr = threadIdx.x >> 6;
#pragma unroll
  for (int i = 0; i < 16; ++i) {
    int r = i * 4 + rr;
    t[r][cc] = in[zoff + (long)(r0 + r) * C + c0 + cc];
  }
  __syncthreads();
#pragma unroll
  for (int i = 0; i < 16; ++i) {
    int orow = i * 4 + rr;
    float v = t[cc][orow];
    long oidx = zoff + (long)(c0 + orow) * R + r0 + cc;
    bf16 hi = (bf16)v;
    oh[oidx] = hi;
    if (SPLIT) ol[oidx] = (bf16)(v - (float)hi);
  }
}

// combine 4 fp32 partials -> bf16
__global__ void k_combine4(const float* __restrict__ p, long pstr,
                           bf16* __restrict__ o) {
  int i = blockIdx.x * 256 + threadIdx.x;
  f32x4 v = ((const f32x4*)p)[i];
#pragma unroll
  for (int zz = 1; zz < 4; ++zz) v += ((const f32x4*)(p + zz * pstr))[i];
  bf16x4 ob;
#pragma unroll
  for (int j = 0; j < 4; ++j) ob[j] = (bf16)v[j];
  ((bf16x4*)o)[i] = ob;
}

// ---------------- 8-phase 256^2 GEMM (R6 value-verified) + XCD swizzle -----
template <int EPI>
__global__ __launch_bounds__(512, 1) void k_gemm8(
    const bf16* __restrict__ A, const bf16* __restrict__ B,
    float* __restrict__ Cf, bf16* __restrict__ Cb,
    const float* __restrict__ bias, int M, int N, int K, int nsplit) {
  __shared__ char lds[131072];
  const int tid = threadIdx.x, w = tid >> 6, l = tid & 63;
  const int l16 = l & 15, lg = l >> 4;
  const int wr = w >> 2, wc = w & 3;
  int bx = blockIdx.x, by = blockIdx.y;
  xcd_swz(bx, by);
  const long bm0 = (long)by * 256, bn0 = (long)bx * 256;
  const int z = blockIdx.z;
  const int ksz = K / nsplit, kbeg = z * ksz;
  const int nt = ksz >> 6;
  const long lK = K;

  const int srow = w * 8 + (l >> 3);
  const int sslot = (l & 7) ^ (l >> 3);

  auto STAGE = [&](int bufp, int isB, int h, int tt) {
    int tc = tt < nt ? tt : nt - 1;
    char* dst = lds + bufp * 65536 + isB * 32768 + h * 16384 + w * 1024;
    const bf16* G = isB ? B : A;
    long r0 = (isB ? bn0 : bm0) + h * 128 + srow;
    const bf16* src = G + r0 * lK + kbeg + tc * 64 + sslot * 8;
    cp16(dst, src);
    cp16(dst + 8192, src + 64 * lK);
  };
  auto LDA = [&](int bufp, int mf, int ks) -> bf16x8 {
    int inrow = (mf & 3) * 32 + wr * 16 + l16;
    int byo = bufp * 65536 + (mf >> 2) * 16384 + inrow * 128 +
              ((((ks << 2) + lg) ^ (inrow & 7)) << 4);
    return *(const bf16x8*)(lds + byo);
  };
  auto LDB = [&](int bufp, int nf, int ks) -> bf16x8 {
    int inrow = (nf & 1) * 64 + wc * 16 + l16;
    int byo = bufp * 65536 + 32768 + (nf >> 1) * 16384 + inrow * 128 +
              ((((ks << 2) + lg) ^ (inrow & 7)) << 4);
    return *(const bf16x8*)(lds + byo);
  };

  f32x4 acc[8][4];
#pragma unroll
  for (int mf = 0; mf < 8; ++mf)
#pragma unroll
    for (int nf = 0; nf < 4; ++nf)
#pragma unroll
      for (int j = 0; j < 4; ++j) acc[mf][nf][j] = 0.f;

  STAGE(0, 0, 0, 0);
  STAGE(0, 1, 0, 0);
  STAGE(0, 0, 1, 0);
  STAGE(0, 1, 1, 0);
  STAGE(1, 1, 0, 1);
  STAGE(1, 0, 1, 1);
  STAGE(1, 1, 1, 1);
  SBAR();
  VMC6();
  GBAR();

  bf16x8 a[4][2], b[2][2];
  for (int t = 0; t < nt; ++t) {
    const int cb = t & 1, nb = cb ^ 1;
#pragma unroll
    for (int mf = 0; mf < 4; ++mf)
#pragma unroll
      for (int ks = 0; ks < 2; ++ks) a[mf][ks] = LDA(cb, mf, ks);
#pragma unroll
    for (int nf = 0; nf < 2; ++nf)
#pragma unroll
      for (int ks = 0; ks < 2; ++ks) b[nf][ks] = LDB(cb, nf, ks);
    STAGE(nb, 0, 0, t + 1);
    SBAR();
    GBAR();
    LGKM0();
    __builtin_amdgcn_s_setprio(1);
#pragma unroll
    for (int mf = 0; mf < 4; ++mf)
#pragma unroll
      for (int nf = 0; nf < 2; ++nf)
#pragma unroll
        for (int ks = 0; ks < 2; ++ks)
          acc[mf][nf] = MFMA(a[mf][ks], b[nf][ks], acc[mf][nf]);
    __builtin_amdgcn_s_setprio(0);
    GBAR();
#pragma unroll
    for (int mf = 0; mf < 4; ++mf)
#pragma unroll
      for (int ks = 0; ks < 2; ++ks) a[mf][ks] = LDA(cb, mf + 4, ks);
    STAGE(cb, 1, 0, t + 2);
    SBAR();
    GBAR();
    LGKM0();
    __builtin_amdgcn_s_setprio(1);
#pragma unroll
    for (int mf = 0; mf < 4; ++mf)
#pragma unroll
      for (int nf = 0; nf < 2; ++nf)
#pragma unroll
        for (int ks = 0; ks < 2; ++ks)
          acc[mf + 4][nf] = MFMA(a[mf][ks], b[nf][ks], acc[mf + 4][nf]);
    __builtin_amdgcn_s_setprio(0);
    GBAR();
#pragma unroll
    for (int nf = 0; nf < 2; ++nf)
#pragma unroll
      for (int ks = 0; ks < 2; ++ks) b[nf][ks] = LDB(cb, nf + 2, ks);
    GBAR();
    LGKM0();
    __builtin_amdgcn_s_setprio(1);
#pragma unroll
    for (int mf = 0; mf < 4; ++mf)
#pragma unroll
      for (int nf = 0; nf < 2; ++nf)
#pragma unroll
        for (int ks = 0; ks < 2; ++ks)
          acc[mf + 4][nf + 2] = MFMA(a[mf][ks], b[nf][ks], acc[mf + 4][nf + 2]);
    __builtin_amdgcn_s_setprio(0);
    GBAR();
#pragma unroll
    for (int mf = 0; mf < 4; ++mf)
#pragma unroll
      for (int ks = 0; ks < 2; ++ks) a[mf][ks] = LDA(cb, mf, ks);
    STAGE(cb, 0, 1, t + 2);
    STAGE(cb, 1, 1, t + 2);
    SBAR();
    VMC6();
    GBAR();
    LGKM0();
    __builtin_amdgcn_s_setprio(1);
#pragma unroll
    for (int mf = 0; mf < 4; ++mf)
#pragma unroll
      for (int nf = 0; nf < 2; ++nf)
#pragma unroll
        for (int ks = 0; ks < 2; ++ks)
          acc[mf][nf + 2] = MFMA(a[mf][ks], b[nf][ks], acc[mf][nf + 2]);
    __builtin_amdgcn_s_setprio(0);
    GBAR();
  }
  asm volatile("s_waitcnt vmcnt(0) lgkmcnt(0)" ::: "memory");

#pragma unroll
  for (int mf = 0; mf < 8; ++mf)
#pragma unroll
    for (int nf = 0; nf < 4; ++nf) {
      long col = bn0 + nf * 64 + wc * 16 + l16;
      float bv = (EPI == 2) ? bias[col] : 0.f;
#pragma unroll
      for (int jj = 0; jj < 4; ++jj) {
        long row = bm0 + mf * 32 + wr * 16 + lg * 4 + jj;
        float v = acc[mf][nf][jj];
        if (EPI == 0) {
          Cf[(long)z * M * N + row * N + col] = v;
        } else {
          v = fmaxf(v + bv, 0.f);
          Cb[row * N + col] = (bf16)v;
        }
      }
    }
}

// ---------------- 8-phase split-precision GEMM (QK proj) + XCD swizzle -----
__global__ __launch_bounds__(512, 1) void k_split8(
    const bf16* __restrict__ Ah_g, const bf16* __restrict__ Al_g,
    const bf16* __restrict__ Bh_g, const bf16* __restrict__ Bl_g,
    bf16* __restrict__ Ch, bf16* __restrict__ Cl,
    int M, int N, int K, float scale, int scale_ncols) {
  __shared__ char lds[98304];
  const int tid = threadIdx.x, w = tid >> 6, l = tid & 63;
  const int l16 = l & 15, lg = l >> 4;
  const int wr = w >> 2, wc = w & 3;
  int bx = blockIdx.x, by = blockIdx.y;
  xcd_swz(bx, by);
  const long bm0 = (long)by * 128, bn0 = (long)bx * 256;
  const int nt = K >> 5;
  const long lK = K;

  const int srcrow = tid >> 2;
  const int ss = (tid & 3) ^ ((tid >> 3) & 3);

  auto STG_A = [&](int bufp, int isLo, int tt) {
    int tc = tt < nt ? tt : nt - 1;
    char* dst = lds + bufp * 49152 + isLo * 8192 + tid * 16;
    const bf16* G = isLo ? Al_g : Ah_g;
    cp16(dst, &G[(bm0 + srcrow) * lK + tc * 32 + ss * 8]);
  };
  auto STG_B = [&](int bufp, int isLo, int half, int tt) {
    int tc = tt < nt ? tt : nt - 1;
    char* dst = lds + bufp * 49152 + 16384 + isLo * 16384 + half * 8192 + tid * 16;
    const bf16* G = isLo ? Bl_g : Bh_g;
    cp16(dst, &G[(bn0 + half * 128 + srcrow) * lK + tc * 32 + ss * 8]);
  };
  auto LDA8 = [&](int bufp, int mf, int isLo) -> bf16x8 {
    int row = mf * 32 + wr * 16 + l16;
    int byo = bufp * 49152 + isLo * 8192 + row * 64 +
              ((lg ^ ((row >> 1) & 3)) << 4);
    return *(const bf16x8*)(lds + byo);
  };
  auto LDB8 = [&](int bufp, int nf, int isLo) -> bf16x8 {
    int row = nf * 64 + wc * 16 + l16;
    int byo = bufp * 49152 + 16384 + isLo * 16384 + row * 64 +
              ((lg ^ ((row >> 1) & 3)) << 4);
    return *(const bf16x8*)(lds + byo);
  };

  f32x4 acc[4][4];
#pragma unroll
  for (int mf = 0; mf < 4; ++mf)
#pragma unroll
    for (int nf = 0; nf < 4; ++nf)
#pragma unroll
      for (int j = 0; j < 4; ++j) acc[mf][nf][j] = 0.f;

  STG_B(0, 0, 0, 0); STG_B(0, 1, 0, 0);
  STG_A(0, 0, 0);    STG_A(0, 1, 0);
  STG_B(0, 0, 1, 0); STG_B(0, 1, 1, 0);
  STG_B(1, 0, 0, 1); STG_B(1, 1, 0, 1);
  STG_A(1, 0, 1);    STG_A(1, 1, 1);
  STG_B(1, 0, 1, 1); STG_B(1, 1, 1, 1);
  SBAR();
  VMC6();
  GBAR();

  bf16x8 ah[4], al[4], bh[2], bl[2];
  for (int t = 0; t < nt; ++t) {
    const int cb = t & 1;
    // P1
#pragma unroll
    for (int mf = 0; mf < 2; ++mf) {
      ah[mf] = LDA8(cb, mf, 0);
      al[mf] = LDA8(cb, mf, 1);
    }
#pragma unroll
    for (int nf = 0; nf < 2; ++nf) {
      bh[nf] = LDB8(cb, nf, 0);
      bl[nf] = LDB8(cb, nf, 1);
    }
    SBAR();
    GBAR();
    LGKM0();
    __builtin_amdgcn_s_setprio(1);
#pragma unroll
    for (int mf = 0; mf < 2; ++mf)
#pragma unroll
      for (int nf = 0; nf < 2; ++nf) {
        acc[mf][nf] = MFMA(ah[mf], bh[nf], acc[mf][nf]);
        acc[mf][nf] = MFMA(ah[mf], bl[nf], acc[mf][nf]);
        acc[mf][nf] = MFMA(al[mf], bh[nf], acc[mf][nf]);
      }
    __builtin_amdgcn_s_setprio(0);
    GBAR();
    // P2
#pragma unroll
    for (int mf = 2; mf < 4; ++mf) {
      ah[mf] = LDA8(cb, mf, 0);
      al[mf] = LDA8(cb, mf, 1);
    }
    STG_B(cb, 0, 0, t + 2);
    STG_B(cb, 1, 0, t + 2);
    SBAR();
    GBAR();
    LGKM0();
    __builtin_amdgcn_s_setprio(1);
#pragma unroll
    for (int mf = 2; mf < 4; ++mf)
#pragma unroll
      for (int nf = 0; nf < 2; ++nf) {
        acc[mf][nf] = MFMA(ah[mf], bh[nf], acc[mf][nf]);
        acc[mf][nf] = MFMA(ah[mf], bl[nf], acc[mf][nf]);
        acc[mf][nf] = MFMA(al[mf], bh[nf], acc[mf][nf]);
      }
    __builtin_amdgcn_s_setprio(0);
    GBAR();
    // P3
#pragma unroll
    for (int nf = 0; nf < 2; ++nf) {
      bh[nf] = LDB8(cb, nf + 2, 0);
      bl[nf] = LDB8(cb, nf + 2, 1);
    }
    STG_A(cb, 0, t + 2);
    STG_A(cb, 1, t + 2);
    SBAR();
    GBAR();
    LGKM0();
    __builtin_amdgcn_s_setprio(1);
#pragma unroll
    for (int mf = 2; mf < 4; ++mf)
#pragma unroll
      for (int nf = 0; nf < 2; ++nf) {
        acc[mf][nf + 2] = MFMA(ah[mf], bh[nf], acc[mf][nf + 2]);
        acc[mf][nf + 2] = MFMA(ah[mf], bl[nf], acc[mf][nf + 2]);
        acc[mf][nf + 2] = MFMA(al[mf], bh[nf], acc[mf][nf + 2]);
      }
    __builtin_amdgcn_s_setprio(0);
    GBAR();
    // P4
    STG_B(cb, 0, 1, t + 2);
    STG_B(cb, 1, 1, t + 2);
    SBAR();
    VMC6();
    GBAR();
    __builtin_amdgcn_s_setprio(1);
#pragma unroll
    for (int mf = 0; mf < 2; ++mf)
#pragma unroll
      for (int nf = 0; nf < 2; ++nf) {
        acc[mf][nf + 2] = MFMA(ah[mf], bh[nf], acc[mf][nf + 2]);
        acc[mf][nf + 2] = MFMA(ah[mf], bl[nf], acc[mf][nf + 2]);
        acc[mf][nf + 2] = MFMA(al[mf], bh[nf], acc[mf][nf + 2]);
      }
    __builtin_amdgcn_s_setprio(0);
    GBAR();
  }
  asm volatile("s_waitcnt vmcnt(0) lgkmcnt(0)" ::: "memory");

#pragma unroll
  for (int mf = 0; mf < 4; ++mf)
#pragma unroll
    for (int nf = 0; nf < 4; ++nf) {
      long col = bn0 + nf * 64 + wc * 16 + l16;
      float sc = (col < scale_ncols) ? scale : 1.0f;
#pragma unroll
      for (int j = 0; j < 4; ++j) {
        long row = bm0 + mf * 32 + wr * 16 + lg * 4 + j;
        float v = acc[mf][nf][j] * sc;
        bf16 hi = (bf16)v;
        Ch[row * N + col] = hi;
        Cl[row * N + col] = (bf16)(v - (float)hi);
      }
    }
}

// ---------------- flash attention (R9-exact: aliased P, 3 blk/CU cap) ------
__global__ __launch_bounds__(256, 3) void k_flash(
    const bf16* __restrict__ Qh, const bf16* __restrict__ Ql,
    const bf16* __restrict__ Kh, const bf16* __restrict__ Kl,
    const bf16* __restrict__ Vt, bf16* __restrict__ Oc) {
  __shared__ bf16 sm[24576];  // 48KB: Kh[64][128] Kl[64][128] Vt[128][64]
  bf16* sKh = sm;
  bf16* sKl = sm + 8192;
  bf16* sVt = sm + 16384;
  bf16* sP = sKl;  // aliased: written only after the post-QK barrier
  const int tid = threadIdx.x, w = tid >> 6, l = tid & 63;
  const int l16 = l & 15, lg = l >> 4;
  const int head = blockIdx.y;
  const long q0 = (long)blockIdx.x * 64;

  bf16x8 qh_r[4], ql_r[4];
#pragma unroll
  for (int kk = 0; kk < 4; ++kk) {
    long off = (q0 + w * 16 + l16) * 4096 + head * 128 + kk * 32 + lg * 8;
    qh_r[kk] = *(const bf16x8*)&Qh[off];
    ql_r[kk] = *(const bf16x8*)&Ql[off];
  }

  f32x4 acc_o[8];
#pragma unroll
  for (int n = 0; n < 8; ++n)
#pragma unroll
    for (int j = 0; j < 4; ++j) acc_o[n][j] = 0.f;
  float mrow[4], lrow[4];
#pragma unroll
  for (int j = 0; j < 4; ++j) {
    mrow[j] = NEG_INF;
    lrow[j] = 0.f;
  }

  for (int t0 = 0; t0 < 2048; t0 += 64) {
    __syncthreads();  // P reads (PV) + prior-tile K reads done
#pragma unroll
    for (int i = 0; i < 4; ++i) {
      int c = (w * 4 + i) * 64 + l;
      int rk = c >> 4, sk = (c & 15) ^ (rk & 7);
      long ko = (long)(t0 + rk) * 4096 + head * 128 + sk * 8;
      int db = (w * 4 + i) * 512;
      cp16(&sKh[db], &Kh[ko]);
      cp16(&sKl[db], &Kl[ko]);
      int rv = c >> 3, sv = (c & 7) ^ (rv & 7);
      long vo = (long)(head * 128 + rv) * 2048 + t0 + sv * 8;
      cp16(&sVt[db], &Vt[vo]);
    }
    __syncthreads();

    f32x4 s[4];
#pragma unroll
    for (int n = 0; n < 4; ++n)
#pragma unroll
      for (int j = 0; j < 4; ++j) s[n][j] = 0.f;
    __builtin_amdgcn_s_setprio(1);
#pragma unroll
    for (int kk = 0; kk < 4; ++kk) {
      bf16x8 bh[4], bl[4];
#pragma unroll
      for (int n = 0; n < 4; ++n) {
        int r = n * 16 + l16;
        int byo = r * 256 + (((kk * 4 + lg) ^ (r & 7)) << 4);
        bh[n] = *(const bf16x8*)((const char*)sKh + byo);
        bl[n] = *(const bf16x8*)((const char*)sKl + byo);
      }
#pragma unroll
      for (int n = 0; n < 4; ++n) {
        s[n] = MFMA(qh_r[kk], bh[n], s[n]);
        s[n] = MFMA(qh_r[kk], bl[n], s[n]);
        s[n] = MFMA(ql_r[kk], bh[n], s[n]);
      }
    }
    __builtin_amdgcn_s_setprio(0);
    __syncthreads();  // all QK reads of sKl done before P overwrites it

#pragma unroll
    for (int j = 0; j < 4; ++j) {
      float mx = fmaxf(fmaxf(s[0][j], s[1][j]), fmaxf(s[2][j], s[3][j]));
      mx = fmaxf(mx, __shfl_xor(mx, 1));
      mx = fmaxf(mx, __shfl_xor(mx, 2));
      mx = fmaxf(mx, __shfl_xor(mx, 4));
      mx = fmaxf(mx, __shfl_xor(mx, 8));
      float mo = mrow[j];
      float mn = fmaxf(mo, mx);
      mrow[j] = mn;
      float f = __expf(mo - mn);
      int prow = w * 16 + lg * 4 + j;
      float ssum = 0.f;
#pragma unroll
      for (int n = 0; n < 4; ++n) {
        float p = __expf(s[n][j] - mn);
        ssum += p;
        int byo = prow * 128 + (((n * 16 + l16) * 2) ^ ((prow & 7) << 4));
        *(bf16*)((char*)sP + byo) = (bf16)p;
      }
      ssum += __shfl_xor(ssum, 1);
      ssum += __shfl_xor(ssum, 2);
      ssum += __shfl_xor(ssum, 4);
      ssum += __shfl_xor(ssum, 8);
      lrow[j] = lrow[j] * f + ssum;
#pragma unroll
      for (int n = 0; n < 8; ++n) acc_o[n][j] *= f;
    }

    // PV (each wave reads only its own P rows; no cross-wave P dependency)
    __builtin_amdgcn_s_setprio(1);
#pragma unroll
    for (int kk = 0; kk < 2; ++kk) {
      bf16x8 pa, bv[8];
      {
        int r = w * 16 + l16;
        int byo = r * 128 + (((kk * 4 + lg) ^ (r & 7)) << 4);
        pa = *(const bf16x8*)((const char*)sP + byo);
      }
#pragma unroll
      for (int n = 0; n < 8; ++n) {
        int r = n * 16 + l16;
        int byo = r * 128 + (((kk * 4 + lg) ^ (r & 7)) << 4);
        bv[n] = *(const bf16x8*)((const char*)sVt + byo);
      }
#pragma unroll
      for (int n = 0; n < 8; ++n) acc_o[n] = MFMA(pa, bv[n], acc_o[n]);
    }
    __builtin_amdgcn_s_setprio(0);
  }

#pragma unroll
  for (int j = 0; j < 4; ++j) {
    float rinv = 1.f / lrow[j];
    long row = q0 + w * 16 + lg * 4 + j;
#pragma unroll
    for (int n = 0; n < 8; ++n)
      Oc[row * 2048 + head * 128 + n * 16 + l16] = (bf16)(acc_o[n][j] * rinv);
  }
}

// ---------------- residual + np partials + LayerNorm ----------------
__global__ __launch_bounds__(256) void k_add_ln(
    const float* __restrict__ a, const float* __restrict__ p, long pstr,
    int np, const float* __restrict__ bias, const float* __restrict__ g,
    const float* __restrict__ be, float* __restrict__ o32,
    bf16* __restrict__ obf) {
  __shared__ float red[8];
  int row = blockIdx.x, tid = threadIdx.x;
  const float* pa = a + (long)row * 2048;
  f32x4 v[2];
  float sum = 0.f, sq = 0.f;
#pragma unroll
  for (int i = 0; i < 2; ++i) {
    int idx = i * 1024 + tid * 4;
    v[i] = *(const f32x4*)(pa + idx);
    for (int zz = 0; zz < np; ++zz)
      v[i] += *(const f32x4*)(p + zz * pstr + (long)row * 2048 + idx);
    if (bias != nullptr) v[i] += *(const f32x4*)(bias + idx);
#pragma unroll
    for (int j = 0; j < 4; ++j) {
      sum += v[i][j];
      sq += v[i][j] * v[i][j];
    }
  }
#pragma unroll
  for (int o = 1; o < 64; o <<= 1) {
    sum += __shfl_xor(sum, o);
    sq += __shfl_xor(sq, o);
  }
  int w = tid >> 6;
  if ((tid & 63) == 0) {
    red[w * 2] = sum;
    red[w * 2 + 1] = sq;
  }
  __syncthreads();
  sum = red[0] + red[2] + red[4] + red[6];
  sq = red[1] + red[3] + red[5] + red[7];
  float mu = sum * (1.f / 2048.f);
  float var = sq * (1.f / 2048.f) - mu * mu;
  float rs = rsqrtf(var + 1e-5f);
#pragma unroll
  for (int i = 0; i < 2; ++i) {
    int idx = i * 1024 + tid * 4;
    f32x4 vg = *(const f32x4*)(g + idx);
    f32x4 vb = *(const f32x4*)(be + idx);
    f32x4 o;
#pragma unroll
    for (int j = 0; j < 4; ++j) o[j] = (v[i][j] - mu) * rs * vg[j] + vb[j];
    *(f32x4*)(o32 + (long)row * 2048 + idx) = o;
    if (obf != nullptr) {
      bf16x4 ob;
#pragma unroll
      for (int j = 0; j < 4; ++j) ob[j] = (bf16)o[j];
      *(bf16x4*)(obf + (long)row * 2048 + idx) = ob;
    }
  }
}

// ---------------- launch ----------------
extern "C" void kernel_launch(void* const* d_in, const int* in_sizes, int n_in,
                              void* d_out, int out_size, void* d_ws, size_t ws_size,
                              hipStream_t stream) {
  const float* x    = (const float*)d_in[0];
  const float* wq   = (const float*)d_in[1];
  const float* wk   = (const float*)d_in[2];
  const float* wv   = (const float*)d_in[3];
  const float* wp   = (const float*)d_in[4];
  const float* g1   = (const float*)d_in[5];
  const float* b1   = (const float*)d_in[6];
  const float* fc1w = (const float*)d_in[7];
  const float* fc1b = (const float*)d_in[8];
  const float* fc2w = (const float*)d_in[9];
  const float* fc2b = (const float*)d_in[10];
  const float* g2   = (const float*)d_in[11];
  const float* b2   = (const float*)d_in[12];
  float* out = (float*)d_out;

  char* ws = (char*)d_ws;
  const size_t MB = 1024 * 1024;
  if (ws_size < 216 * MB) return;
  const long W4M = 4L * 1024 * 1024;

  // ADJACENCY CONSTRAINT: qk_bh = [wq^T | wk^T] hi as ONE [4096][2048];
  // qk_bl likewise lo (split8's B operands span both).
  bf16* xh    = (bf16*)(ws + 0 * MB);
  bf16* xl    = (bf16*)(ws + 8 * MB);
  bf16* qk_bh = (bf16*)(ws + 16 * MB);   // 16MB
  bf16* qk_bl = (bf16*)(ws + 32 * MB);   // 16MB
  bf16* wvt   = (bf16*)(ws + 48 * MB);
  bf16* wpt   = (bf16*)(ws + 56 * MB);
  bf16* fc1t  = (bf16*)(ws + 64 * MB);   // 32MB
  bf16* fc2t  = (bf16*)(ws + 96 * MB);   // 32MB
  float* vtp  = (float*)(ws + 128 * MB); // 4x16MB vt partials
  bf16* vtb   = (bf16*)(ws + 192 * MB);  // 8MB
  bf16* qkh   = (bf16*)(ws + 128 * MB);  // 16MB (vtp dead)
  bf16* qkl   = (bf16*)(ws + 144 * MB);  // 16MB
  bf16* cc    = (bf16*)(ws + 200 * MB);  // 8MB concat
  float* aop  = (float*)(ws + 128 * MB); // 4x16MB (qk dead post-flash)
  float* h32  = (float*)(ws + 192 * MB); // 16MB (vtb dead post-flash)
  bf16*  hbf  = (bf16*)(ws + 208 * MB);  // 8MB
  bf16*  ff1  = (bf16*)(ws + 128 * MB);  // 32MB (aop dead after LN1)
  float* ffp  = (float*)(ws + 0 * MB);   // 4x16MB (x/qk_b dead)
  const long PSTR = 4194304L;

  // converts
  k_split_x<<<4096, 256, 0, stream>>>(x, xh, xl);
  k_tcvt<true ><<<dim3(2, 32, 16), 256, 0, stream>>>(wq, qk_bh, qk_bl, 2048, 128);
  k_tcvt<true ><<<dim3(2, 32, 16), 256, 0, stream>>>(wk, qk_bh + W4M, qk_bl + W4M,
                                                     2048, 128);
  k_tcvt<false><<<dim3(2, 32, 16), 256, 0, stream>>>(wv, wvt, nullptr, 2048, 128);
  k_tcvt<false><<<dim3(32, 32, 1), 256, 0, stream>>>(wp, wpt, nullptr, 2048, 2048);
  k_tcvt<false><<<dim3(128, 32, 1), 256, 0, stream>>>(fc1w, fc1t, nullptr, 2048, 8192);
  k_tcvt<false><<<dim3(32, 128, 1), 256, 0, stream>>>(fc2w, fc2t, nullptr, 8192, 2048);

  // V^T = wvt @ xh^T  (8-phase, split-K=4) -> combine to bf16
  k_gemm8<0><<<dim3(8, 8, 4), 512, 0, stream>>>(
      wvt, xh, vtp, nullptr, nullptr, 2048, 2048, 2048, 4);
  k_combine4<<<4096, 256, 0, stream>>>(vtp, PSTR, vtb);
  // fused Q,K projection (8-phase split-precision), 1/sqrt(128) on Q cols
  k_split8<<<dim3(16, 16), 512, 0, stream>>>(
      xh, xl, qk_bh, qk_bl, qkh, qkl, 2048, 4096, 2048,
      0.08838834764831845f, 2048);
  // attention -> concat
  k_flash<<<dim3(32, 16), 256, 0, stream>>>(qkh, qkl, qkh + 2048, qkl + 2048,
                                            vtb, cc);
  // out projection (8-phase, split-K=4)
  k_gemm8<0><<<dim3(8, 8, 4), 512, 0, stream>>>(
      cc, wpt, aop, nullptr, nullptr, 2048, 2048, 2048, 4);
  // h = LN(x + sum aop)
  k_add_ln<<<2048, 256, 0, stream>>>(x, aop, PSTR, 4, nullptr, g1, b1, h32, hbf);
  // ff1 = relu(h @ fc1 + b1)
  k_gemm8<2><<<dim3(32, 8, 1), 512, 0, stream>>>(
      hbf, fc1t, nullptr, ff1, fc1b, 2048, 8192, 2048, 1);
  // ff2 partials (8-phase, split-K=4 over K=8192)
  k_gemm8<0><<<dim3(8, 8, 4), 512, 0, stream>>>(
      ff1, fc2t, ffp, nullptr, nullptr, 2048, 2048, 8192, 4);
  // out = LN(h + sum ffp + fc2b)
  k_add_ln<<<2048, 256, 0, stream>>>(h32, ffp, PSTR, 4, fc2b, g2, b2, out, nullptr);
}

// Round 15
// 514.674 us; speedup vs baseline: 1.0705x; 1.0074x over previous
//
#include <hip/hip_runtime.h>

// TransformerBlock fused pipeline for MI355X (gfx950).
// SEQ=2048, D_MODEL=2048, H=16, DK=DV=128, DFF=8192. fp32 in/out.
//
// R15: R14's split8-tail vt-combine RACED (split8 epilogue writes qkh over
// vtp[z=0..1] while other blocks' tails still read vtp -- fusing kernels
// merges liveness windows). Combine reverted to its own dispatch (R13
// ordering). k_tcvt_qkv fusion kept (audited alias-free). 13 dispatches.

typedef __bf16 bf16;
typedef __attribute__((ext_vector_type(8))) __bf16 bf16x8;
typedef __attribute__((ext_vector_type(4))) __bf16 bf16x4;
typedef __attribute__((ext_vector_type(4))) float f32x4;

#define MFMA(a, b, c) __builtin_amdgcn_mfma_f32_16x16x32_bf16((a), (b), (c), 0, 0, 0)
#define NEG_INF (-3.402823466e38f)

__device__ __forceinline__ void cp16(void* lds, const void* g) {
  __builtin_amdgcn_global_load_lds(
      (const __attribute__((address_space(1))) unsigned int*)g,
      (__attribute__((address_space(3))) unsigned int*)lds, 16, 0, 0);
}

#define SBAR() __builtin_amdgcn_sched_barrier(0)
#define GBAR()                              \
  do {                                      \
    asm volatile("" ::: "memory");          \
    __builtin_amdgcn_s_barrier();           \
    asm volatile("" ::: "memory");          \
  } while (0)
#define LGKM0()                                         \
  do {                                                  \
    asm volatile("s_waitcnt lgkmcnt(0)" ::: "memory");  \
    __builtin_amdgcn_sched_barrier(0);                  \
  } while (0)
#define VMC6()                                          \
  do {                                                  \
    asm volatile("s_waitcnt vmcnt(6)" ::: "memory");    \
    __builtin_amdgcn_sched_barrier(0);                  \
  } while (0)

// bijective XCD swizzle for 2D grids with (gx*gy)%8==0
__device__ __forceinline__ void xcd_swz(int& bx, int& by) {
  const int gx = gridDim.x, nwg = gx * gridDim.y;
  const int lid = by * gx + bx;
  const int swz = (lid & 7) * (nwg >> 3) + (lid >> 3);
  bx = swz % gx;
  by = swz / gx;
}

// ---------------- fused converts ----------------
// z in [0,48): sel = z>>4 routes {wq, wk, wv}; zz = z&15 is the head.
// Tail (grid-stride): x fp32 -> xh/xl bf16 split. Writes are alias-free:
// xh/xl (0-16MB), qk_b (16-48MB), wvt (48-56MB).
__global__ void k_tcvt_qkv(const float* __restrict__ wq,
                           const float* __restrict__ wk,
                           const float* __restrict__ wv,
                           bf16* __restrict__ bh, bf16* __restrict__ bl,
                           bf16* __restrict__ vt,
                           const float* __restrict__ x,
                           bf16* __restrict__ xh, bf16* __restrict__ xl) {
  __shared__ float t[64][65];
  const long W4M = 4L * 1024 * 1024;
  int sel = blockIdx.z >> 4, zz = blockIdx.z & 15;
  const float* in = (sel == 0) ? wq : ((sel == 1) ? wk : wv);
  bf16* oh = (sel == 0) ? bh : ((sel == 1) ? bh + W4M : vt);
  bf16* ol = (sel == 0) ? bl : ((sel == 1) ? bl + W4M : nullptr);
  const int R = 2048, C = 128;
  long zoff = (long)zz * R * C;
  int c0 = blockIdx.x * 64, r0 = blockIdx.y * 64;
  int cc = threadIdx.x & 63, rr = threadIdx.x >> 6;
#pragma unroll
  for (int i = 0; i < 16; ++i) {
    int r = i * 4 + rr;
    t[r][cc] = in[zoff + (long)(r0 + r) * C + c0 + cc];
  }
  __syncthreads();
#pragma unroll
  for (int i = 0; i < 16; ++i) {
    int orow = i * 4 + rr;
    float v = t[cc][orow];
    long oidx = zoff + (long)(c0 + orow) * R + r0 + cc;
    bf16 hi = (bf16)v;
    oh[oidx] = hi;
    if (ol != nullptr) ol[oidx] = (bf16)(v - (float)hi);
  }
  // tail: x -> xh/xl (1,048,576 f32x4 groups over 3072x256 threads)
  long gtid = (long)(blockIdx.z * gridDim.y * gridDim.x +
                     blockIdx.y * gridDim.x + blockIdx.x) * 256 + threadIdx.x;
  for (long i = gtid; i < 1048576L; i += 786432L) {
    f32x4 v = ((const f32x4*)x)[i];
    bf16x4 h, l;
#pragma unroll
    for (int j = 0; j < 4; ++j) {
      bf16 hi = (bf16)v[j];
      h[j] = hi;
      l[j] = (bf16)(v[j] - (float)hi);
    }
    ((bf16x4*)xh)[i] = h;
    ((bf16x4*)xl)[i] = l;
  }
}

template <bool SPLIT>
__global__ void k_tcvt(const float* __restrict__ in, bf16* __restrict__ oh,
                       bf16* __restrict__ ol, int R, int C) {
  __shared__ float t[64][65];
  long zoff = (long)blockIdx.z * R * C;
  int c0 = blockIdx.x * 64, r0 = blockIdx.y * 64;
  int cc = threadIdx.x & 63, rr = threadIdx.x >> 6;
#pragma unroll
  for (int i = 0; i < 16; ++i) {
    int r = i * 4 + rr;
    t[r][cc] = in[zoff + (long)(r0 + r) * C + c0 + cc];
  }
  __syncthreads();
#pragma unroll
  for (int i = 0; i < 16; ++i) {
    int orow = i * 4 + rr;
    float v = t[cc][orow];
    long oidx = zoff + (long)(c0 + orow) * R + r0 + cc;
    bf16 hi = (bf16)v;
    oh[oidx] = hi;
    if (SPLIT) ol[oidx] = (bf16)(v - (float)hi);
  }
}

// combine 4 fp32 partials -> bf16 (own dispatch: vtp must be fully dead
// before split8 overwrites its region with qkh/qkl)
__global__ void k_combine4(const float* __restrict__ p, long pstr,
                           bf16* __restrict__ o) {
  int i = blockIdx.x * 256 + threadIdx.x;
  f32x4 v = ((const f32x4*)p)[i];
#pragma unroll
  for (int zz = 1; zz < 4; ++zz) v += ((const f32x4*)(p + zz * pstr))[i];
  bf16x4 ob;
#pragma unroll
  for (int j = 0; j < 4; ++j) ob[j] = (bf16)v[j];
  ((bf16x4*)o)[i] = ob;
}

// ---------------- 8-phase 256^2 GEMM (R6 value-verified) + XCD swizzle -----
template <int EPI>
__global__ __launch_bounds__(512, 1) void k_gemm8(
    const bf16* __restrict__ A, const bf16* __restrict__ B,
    float* __restrict__ Cf, bf16* __restrict__ Cb,
    const float* __restrict__ bias, int M, int N, int K, int nsplit) {
  __shared__ char lds[131072];
  const int tid = threadIdx.x, w = tid >> 6, l = tid & 63;
  const int l16 = l & 15, lg = l >> 4;
  const int wr = w >> 2, wc = w & 3;
  int bx = blockIdx.x, by = blockIdx.y;
  xcd_swz(bx, by);
  const long bm0 = (long)by * 256, bn0 = (long)bx * 256;
  const int z = blockIdx.z;
  const int ksz = K / nsplit, kbeg = z * ksz;
  const int nt = ksz >> 6;
  const long lK = K;

  const int srow = w * 8 + (l >> 3);
  const int sslot = (l & 7) ^ (l >> 3);

  auto STAGE = [&](int bufp, int isB, int h, int tt) {
    int tc = tt < nt ? tt : nt - 1;
    char* dst = lds + bufp * 65536 + isB * 32768 + h * 16384 + w * 1024;
    const bf16* G = isB ? B : A;
    long r0 = (isB ? bn0 : bm0) + h * 128 + srow;
    const bf16* src = G + r0 * lK + kbeg + tc * 64 + sslot * 8;
    cp16(dst, src);
    cp16(dst + 8192, src + 64 * lK);
  };
  auto LDA = [&](int bufp, int mf, int ks) -> bf16x8 {
    int inrow = (mf & 3) * 32 + wr * 16 + l16;
    int byo = bufp * 65536 + (mf >> 2) * 16384 + inrow * 128 +
              ((((ks << 2) + lg) ^ (inrow & 7)) << 4);
    return *(const bf16x8*)(lds + byo);
  };
  auto LDB = [&](int bufp, int nf, int ks) -> bf16x8 {
    int inrow = (nf & 1) * 64 + wc * 16 + l16;
    int byo = bufp * 65536 + 32768 + (nf >> 1) * 16384 + inrow * 128 +
              ((((ks << 2) + lg) ^ (inrow & 7)) << 4);
    return *(const bf16x8*)(lds + byo);
  };

  f32x4 acc[8][4];
#pragma unroll
  for (int mf = 0; mf < 8; ++mf)
#pragma unroll
    for (int nf = 0; nf < 4; ++nf)
#pragma unroll
      for (int j = 0; j < 4; ++j) acc[mf][nf][j] = 0.f;

  STAGE(0, 0, 0, 0);
  STAGE(0, 1, 0, 0);
  STAGE(0, 0, 1, 0);
  STAGE(0, 1, 1, 0);
  STAGE(1, 1, 0, 1);
  STAGE(1, 0, 1, 1);
  STAGE(1, 1, 1, 1);
  SBAR();
  VMC6();
  GBAR();

  bf16x8 a[4][2], b[2][2];
  for (int t = 0; t < nt; ++t) {
    const int cb = t & 1, nb = cb ^ 1;
#pragma unroll
    for (int mf = 0; mf < 4; ++mf)
#pragma unroll
      for (int ks = 0; ks < 2; ++ks) a[mf][ks] = LDA(cb, mf, ks);
#pragma unroll
    for (int nf = 0; nf < 2; ++nf)
#pragma unroll
      for (int ks = 0; ks < 2; ++ks) b[nf][ks] = LDB(cb, nf, ks);
    STAGE(nb, 0, 0, t + 1);
    SBAR();
    GBAR();
    LGKM0();
    __builtin_amdgcn_s_setprio(1);
#pragma unroll
    for (int mf = 0; mf < 4; ++mf)
#pragma unroll
      for (int nf = 0; nf < 2; ++nf)
#pragma unroll
        for (int ks = 0; ks < 2; ++ks)
          acc[mf][nf] = MFMA(a[mf][ks], b[nf][ks], acc[mf][nf]);
    __builtin_amdgcn_s_setprio(0);
    GBAR();
#pragma unroll
    for (int mf = 0; mf < 4; ++mf)
#pragma unroll
      for (int ks = 0; ks < 2; ++ks) a[mf][ks] = LDA(cb, mf + 4, ks);
    STAGE(cb, 1, 0, t + 2);
    SBAR();
    GBAR();
    LGKM0();
    __builtin_amdgcn_s_setprio(1);
#pragma unroll
    for (int mf = 0; mf < 4; ++mf)
#pragma unroll
      for (int nf = 0; nf < 2; ++nf)
#pragma unroll
        for (int ks = 0; ks < 2; ++ks)
          acc[mf + 4][nf] = MFMA(a[mf][ks], b[nf][ks], acc[mf + 4][nf]);
    __builtin_amdgcn_s_setprio(0);
    GBAR();
#pragma unroll
    for (int nf = 0; nf < 2; ++nf)
#pragma unroll
      for (int ks = 0; ks < 2; ++ks) b[nf][ks] = LDB(cb, nf + 2, ks);
    GBAR();
    LGKM0();
    __builtin_amdgcn_s_setprio(1);
#pragma unroll
    for (int mf = 0; mf < 4; ++mf)
#pragma unroll
      for (int nf = 0; nf < 2; ++nf)
#pragma unroll
        for (int ks = 0; ks < 2; ++ks)
          acc[mf + 4][nf + 2] = MFMA(a[mf][ks], b[nf][ks], acc[mf + 4][nf + 2]);
    __builtin_amdgcn_s_setprio(0);
    GBAR();
#pragma unroll
    for (int mf = 0; mf < 4; ++mf)
#pragma unroll
      for (int ks = 0; ks < 2; ++ks) a[mf][ks] = LDA(cb, mf, ks);
    STAGE(cb, 0, 1, t + 2);
    STAGE(cb, 1, 1, t + 2);
    SBAR();
    VMC6();
    GBAR();
    LGKM0();
    __builtin_amdgcn_s_setprio(1);
#pragma unroll
    for (int mf = 0; mf < 4; ++mf)
#pragma unroll
      for (int nf = 0; nf < 2; ++nf)
#pragma unroll
        for (int ks = 0; ks < 2; ++ks)
          acc[mf][nf + 2] = MFMA(a[mf][ks], b[nf][ks], acc[mf][nf + 2]);
    __builtin_amdgcn_s_setprio(0);
    GBAR();
  }
  asm volatile("s_waitcnt vmcnt(0) lgkmcnt(0)" ::: "memory");

#pragma unroll
  for (int mf = 0; mf < 8; ++mf)
#pragma unroll
    for (int nf = 0; nf < 4; ++nf) {
      long col = bn0 + nf * 64 + wc * 16 + l16;
      float bv = (EPI == 2) ? bias[col] : 0.f;
#pragma unroll
      for (int jj = 0; jj < 4; ++jj) {
        long row = bm0 + mf * 32 + wr * 16 + lg * 4 + jj;
        float v = acc[mf][nf][jj];
        if (EPI == 0) {
          Cf[(long)z * M * N + row * N + col] = v;
        } else {
          v = fmaxf(v + bv, 0.f);
          Cb[row * N + col] = (bf16)v;
        }
      }
    }
}

// ---------------- 8-phase split-precision GEMM (QK proj) + XCD swizzle -----
__global__ __launch_bounds__(512, 1) void k_split8(
    const bf16* __restrict__ Ah_g, const bf16* __restrict__ Al_g,
    const bf16* __restrict__ Bh_g, const bf16* __restrict__ Bl_g,
    bf16* __restrict__ Ch, bf16* __restrict__ Cl,
    int M, int N, int K, float scale, int scale_ncols) {
  __shared__ char lds[98304];
  const int tid = threadIdx.x, w = tid >> 6, l = tid & 63;
  const int l16 = l & 15, lg = l >> 4;
  const int wr = w >> 2, wc = w & 3;
  int bx = blockIdx.x, by = blockIdx.y;
  xcd_swz(bx, by);
  const long bm0 = (long)by * 128, bn0 = (long)bx * 256;
  const int nt = K >> 5;
  const long lK = K;

  const int srcrow = tid >> 2;
  const int ss = (tid & 3) ^ ((tid >> 3) & 3);

  auto STG_A = [&](int bufp, int isLo, int tt) {
    int tc = tt < nt ? tt : nt - 1;
    char* dst = lds + bufp * 49152 + isLo * 8192 + tid * 16;
    const bf16* G = isLo ? Al_g : Ah_g;
    cp16(dst, &G[(bm0 + srcrow) * lK + tc * 32 + ss * 8]);
  };
  auto STG_B = [&](int bufp, int isLo, int half, int tt) {
    int tc = tt < nt ? tt : nt - 1;
    char* dst = lds + bufp * 49152 + 16384 + isLo * 16384 + half * 8192 + tid * 16;
    const bf16* G = isLo ? Bl_g : Bh_g;
    cp16(dst, &G[(bn0 + half * 128 + srcrow) * lK + tc * 32 + ss * 8]);
  };
  auto LDA8 = [&](int bufp, int mf, int isLo) -> bf16x8 {
    int row = mf * 32 + wr * 16 + l16;
    int byo = bufp * 49152 + isLo * 8192 + row * 64 +
              ((lg ^ ((row >> 1) & 3)) << 4);
    return *(const bf16x8*)(lds + byo);
  };
  auto LDB8 = [&](int bufp, int nf, int isLo) -> bf16x8 {
    int row = nf * 64 + wc * 16 + l16;
    int byo = bufp * 49152 + 16384 + isLo * 16384 + row * 64 +
              ((lg ^ ((row >> 1) & 3)) << 4);
    return *(const bf16x8*)(lds + byo);
  };

  f32x4 acc[4][4];
#pragma unroll
  for (int mf = 0; mf < 4; ++mf)
#pragma unroll
    for (int nf = 0; nf < 4; ++nf)
#pragma unroll
      for (int j = 0; j < 4; ++j) acc[mf][nf][j] = 0.f;

  STG_B(0, 0, 0, 0); STG_B(0, 1, 0, 0);
  STG_A(0, 0, 0);    STG_A(0, 1, 0);
  STG_B(0, 0, 1, 0); STG_B(0, 1, 1, 0);
  STG_B(1, 0, 0, 1); STG_B(1, 1, 0, 1);
  STG_A(1, 0, 1);    STG_A(1, 1, 1);
  STG_B(1, 0, 1, 1); STG_B(1, 1, 1, 1);
  SBAR();
  VMC6();
  GBAR();

  bf16x8 ah[4], al[4], bh[2], bl[2];
  for (int t = 0; t < nt; ++t) {
    const int cb = t & 1;
    // P1
#pragma unroll
    for (int mf = 0; mf < 2; ++mf) {
      ah[mf] = LDA8(cb, mf, 0);
      al[mf] = LDA8(cb, mf, 1);
    }
#pragma unroll
    for (int nf = 0; nf < 2; ++nf) {
      bh[nf] = LDB8(cb, nf, 0);
      bl[nf] = LDB8(cb, nf, 1);
    }
    SBAR();
    GBAR();
    LGKM0();
    __builtin_amdgcn_s_setprio(1);
#pragma unroll
    for (int mf = 0; mf < 2; ++mf)
#pragma unroll
      for (int nf = 0; nf < 2; ++nf) {
        acc[mf][nf] = MFMA(ah[mf], bh[nf], acc[mf][nf]);
        acc[mf][nf] = MFMA(ah[mf], bl[nf], acc[mf][nf]);
        acc[mf][nf] = MFMA(al[mf], bh[nf], acc[mf][nf]);
      }
    __builtin_amdgcn_s_setprio(0);
    GBAR();
    // P2
#pragma unroll
    for (int mf = 2; mf < 4; ++mf) {
      ah[mf] = LDA8(cb, mf, 0);
      al[mf] = LDA8(cb, mf, 1);
    }
    STG_B(cb, 0, 0, t + 2);
    STG_B(cb, 1, 0, t + 2);
    SBAR();
    GBAR();
    LGKM0();
    __builtin_amdgcn_s_setprio(1);
#pragma unroll
    for (int mf = 2; mf < 4; ++mf)
#pragma unroll
      for (int nf = 0; nf < 2; ++nf) {
        acc[mf][nf] = MFMA(ah[mf], bh[nf], acc[mf][nf]);
        acc[mf][nf] = MFMA(ah[mf], bl[nf], acc[mf][nf]);
        acc[mf][nf] = MFMA(al[mf], bh[nf], acc[mf][nf]);
      }
    __builtin_amdgcn_s_setprio(0);
    GBAR();
    // P3
#pragma unroll
    for (int nf = 0; nf < 2; ++nf) {
      bh[nf] = LDB8(cb, nf + 2, 0);
      bl[nf] = LDB8(cb, nf + 2, 1);
    }
    STG_A(cb, 0, t + 2);
    STG_A(cb, 1, t + 2);
    SBAR();
    GBAR();
    LGKM0();
    __builtin_amdgcn_s_setprio(1);
#pragma unroll
    for (int mf = 2; mf < 4; ++mf)
#pragma unroll
      for (int nf = 0; nf < 2; ++nf) {
        acc[mf][nf + 2] = MFMA(ah[mf], bh[nf], acc[mf][nf + 2]);
        acc[mf][nf + 2] = MFMA(ah[mf], bl[nf], acc[mf][nf + 2]);
        acc[mf][nf + 2] = MFMA(al[mf], bh[nf], acc[mf][nf + 2]);
      }
    __builtin_amdgcn_s_setprio(0);
    GBAR();
    // P4
    STG_B(cb, 0, 1, t + 2);
    STG_B(cb, 1, 1, t + 2);
    SBAR();
    VMC6();
    GBAR();
    __builtin_amdgcn_s_setprio(1);
#pragma unroll
    for (int mf = 0; mf < 2; ++mf)
#pragma unroll
      for (int nf = 0; nf < 2; ++nf) {
        acc[mf][nf + 2] = MFMA(ah[mf], bh[nf], acc[mf][nf + 2]);
        acc[mf][nf + 2] = MFMA(ah[mf], bl[nf], acc[mf][nf + 2]);
        acc[mf][nf + 2] = MFMA(al[mf], bh[nf], acc[mf][nf + 2]);
      }
    __builtin_amdgcn_s_setprio(0);
    GBAR();
  }
  asm volatile("s_waitcnt vmcnt(0) lgkmcnt(0)" ::: "memory");

#pragma unroll
  for (int mf = 0; mf < 4; ++mf)
#pragma unroll
    for (int nf = 0; nf < 4; ++nf) {
      long col = bn0 + nf * 64 + wc * 16 + l16;
      float sc = (col < scale_ncols) ? scale : 1.0f;
#pragma unroll
      for (int j = 0; j < 4; ++j) {
        long row = bm0 + mf * 32 + wr * 16 + lg * 4 + j;
        float v = acc[mf][nf][j] * sc;
        bf16 hi = (bf16)v;
        Ch[row * N + col] = hi;
        Cl[row * N + col] = (bf16)(v - (float)hi);
      }
    }
}

// ---------------- flash attention (R9-exact: aliased P, 3 blk/CU cap) ------
__global__ __launch_bounds__(256, 3) void k_flash(
    const bf16* __restrict__ Qh, const bf16* __restrict__ Ql,
    const bf16* __restrict__ Kh, const bf16* __restrict__ Kl,
    const bf16* __restrict__ Vt, bf16* __restrict__ Oc) {
  __shared__ bf16 sm[24576];  // 48KB: Kh[64][128] Kl[64][128] Vt[128][64]
  bf16* sKh = sm;
  bf16* sKl = sm + 8192;
  bf16* sVt = sm + 16384;
  bf16* sP = sKl;  // aliased: written only after the post-QK barrier
  const int tid = threadIdx.x, w = tid >> 6, l = tid & 63;
  const int l16 = l & 15, lg = l >> 4;
  const int head = blockIdx.y;
  const long q0 = (long)blockIdx.x * 64;

  bf16x8 qh_r[4], ql_r[4];
#pragma unroll
  for (int kk = 0; kk < 4; ++kk) {
    long off = (q0 + w * 16 + l16) * 4096 + head * 128 + kk * 32 + lg * 8;
    qh_r[kk] = *(const bf16x8*)&Qh[off];
    ql_r[kk] = *(const bf16x8*)&Ql[off];
  }

  f32x4 acc_o[8];
#pragma unroll
  for (int n = 0; n < 8; ++n)
#pragma unroll
    for (int j = 0; j < 4; ++j) acc_o[n][j] = 0.f;
  float mrow[4], lrow[4];
#pragma unroll
  for (int j = 0; j < 4; ++j) {
    mrow[j] = NEG_INF;
    lrow[j] = 0.f;
  }

  for (int t0 = 0; t0 < 2048; t0 += 64) {
    __syncthreads();
#pragma unroll
    for (int i = 0; i < 4; ++i) {
      int c = (w * 4 + i) * 64 + l;
      int rk = c >> 4, sk = (c & 15) ^ (rk & 7);
      long ko = (long)(t0 + rk) * 4096 + head * 128 + sk * 8;
      int db = (w * 4 + i) * 512;
      cp16(&sKh[db], &Kh[ko]);
      cp16(&sKl[db], &Kl[ko]);
      int rv = c >> 3, sv = (c & 7) ^ (rv & 7);
      long vo = (long)(head * 128 + rv) * 2048 + t0 + sv * 8;
      cp16(&sVt[db], &Vt[vo]);
    }
    __syncthreads();

    f32x4 s[4];
#pragma unroll
    for (int n = 0; n < 4; ++n)
#pragma unroll
      for (int j = 0; j < 4; ++j) s[n][j] = 0.f;
    __builtin_amdgcn_s_setprio(1);
#pragma unroll
    for (int kk = 0; kk < 4; ++kk) {
      bf16x8 bh[4], bl[4];
#pragma unroll
      for (int n = 0; n < 4; ++n) {
        int r = n * 16 + l16;
        int byo = r * 256 + (((kk * 4 + lg) ^ (r & 7)) << 4);
        bh[n] = *(const bf16x8*)((const char*)sKh + byo);
        bl[n] = *(const bf16x8*)((const char*)sKl + byo);
      }
#pragma unroll
      for (int n = 0; n < 4; ++n) {
        s[n] = MFMA(qh_r[kk], bh[n], s[n]);
        s[n] = MFMA(qh_r[kk], bl[n], s[n]);
        s[n] = MFMA(ql_r[kk], bh[n], s[n]);
      }
    }
    __builtin_amdgcn_s_setprio(0);
    __syncthreads();  // all QK reads of sKl done before P overwrites it

#pragma unroll
    for (int j = 0; j < 4; ++j) {
      float mx = fmaxf(fmaxf(s[0][j], s[1][j]), fmaxf(s[2][j], s[3][j]));
      mx = fmaxf(mx, __shfl_xor(mx, 1));
      mx = fmaxf(mx, __shfl_xor(mx, 2));
      mx = fmaxf(mx, __shfl_xor(mx, 4));
      mx = fmaxf(mx, __shfl_xor(mx, 8));
      float mo = mrow[j];
      float mn = fmaxf(mo, mx);
      mrow[j] = mn;
      float f = __expf(mo - mn);
      int prow = w * 16 + lg * 4 + j;
      float ssum = 0.f;
#pragma unroll
      for (int n = 0; n < 4; ++n) {
        float p = __expf(s[n][j] - mn);
        ssum += p;
        int byo = prow * 128 + (((n * 16 + l16) * 2) ^ ((prow & 7) << 4));
        *(bf16*)((char*)sP + byo) = (bf16)p;
      }
      ssum += __shfl_xor(ssum, 1);
      ssum += __shfl_xor(ssum, 2);
      ssum += __shfl_xor(ssum, 4);
      ssum += __shfl_xor(ssum, 8);
      lrow[j] = lrow[j] * f + ssum;
#pragma unroll
      for (int n = 0; n < 8; ++n) acc_o[n][j] *= f;
    }

    __builtin_amdgcn_s_setprio(1);
#pragma unroll
    for (int kk = 0; kk < 2; ++kk) {
      bf16x8 pa, bv[8];
      {
        int r = w * 16 + l16;
        int byo = r * 128 + (((kk * 4 + lg) ^ (r & 7)) << 4);
        pa = *(const bf16x8*)((const char*)sP + byo);
      }
#pragma unroll
      for (int n = 0; n < 8; ++n) {
        int r = n * 16 + l16;
        int byo = r * 128 + (((kk * 4 + lg) ^ (r & 7)) << 4);
        bv[n] = *(const bf16x8*)((const char*)sVt + byo);
      }
#pragma unroll
      for (int n = 0; n < 8; ++n) acc_o[n] = MFMA(pa, bv[n], acc_o[n]);
    }
    __builtin_amdgcn_s_setprio(0);
  }

#pragma unroll
  for (int j = 0; j < 4; ++j) {
    float rinv = 1.f / lrow[j];
    long row = q0 + w * 16 + lg * 4 + j;
#pragma unroll
    for (int n = 0; n < 8; ++n)
      Oc[row * 2048 + head * 128 + n * 16 + l16] = (bf16)(acc_o[n][j] * rinv);
  }
}

// ---------------- residual + np partials + LayerNorm ----------------
__global__ __launch_bounds__(256) void k_add_ln(
    const float* __restrict__ a, const float* __restrict__ p, long pstr,
    int np, const float* __restrict__ bias, const float* __restrict__ g,
    const float* __restrict__ be, float* __restrict__ o32,
    bf16* __restrict__ obf) {
  __shared__ float red[8];
  int row = blockIdx.x, tid = threadIdx.x;
  const float* pa = a + (long)row * 2048;
  f32x4 v[2];
  float sum = 0.f, sq = 0.f;
#pragma unroll
  for (int i = 0; i < 2; ++i) {
    int idx = i * 1024 + tid * 4;
    v[i] = *(const f32x4*)(pa + idx);
    for (int zz = 0; zz < np; ++zz)
      v[i] += *(const f32x4*)(p + zz * pstr + (long)row * 2048 + idx);
    if (bias != nullptr) v[i] += *(const f32x4*)(bias + idx);
#pragma unroll
    for (int j = 0; j < 4; ++j) {
      sum += v[i][j];
      sq += v[i][j] * v[i][j];
    }
  }
#pragma unroll
  for (int o = 1; o < 64; o <<= 1) {
    sum += __shfl_xor(sum, o);
    sq += __shfl_xor(sq, o);
  }
  int w = tid >> 6;
  if ((tid & 63) == 0) {
    red[w * 2] = sum;
    red[w * 2 + 1] = sq;
  }
  __syncthreads();
  sum = red[0] + red[2] + red[4] + red[6];
  sq = red[1] + red[3] + red[5] + red[7];
  float mu = sum * (1.f / 2048.f);
  float var = sq * (1.f / 2048.f) - mu * mu;
  float rs = rsqrtf(var + 1e-5f);
#pragma unroll
  for (int i = 0; i < 2; ++i) {
    int idx = i * 1024 + tid * 4;
    f32x4 vg = *(const f32x4*)(g + idx);
    f32x4 vb = *(const f32x4*)(be + idx);
    f32x4 o;
#pragma unroll
    for (int j = 0; j < 4; ++j) o[j] = (v[i][j] - mu) * rs * vg[j] + vb[j];
    *(f32x4*)(o32 + (long)row * 2048 + idx) = o;
    if (obf != nullptr) {
      bf16x4 ob;
#pragma unroll
      for (int j = 0; j < 4; ++j) ob[j] = (bf16)o[j];
      *(bf16x4*)(obf + (long)row * 2048 + idx) = ob;
    }
  }
}

// ---------------- launch ----------------
extern "C" void kernel_launch(void* const* d_in, const int* in_sizes, int n_in,
                              void* d_out, int out_size, void* d_ws, size_t ws_size,
                              hipStream_t stream) {
  const float* x    = (const float*)d_in[0];
  const float* wq   = (const float*)d_in[1];
  const float* wk   = (const float*)d_in[2];
  const float* wv   = (const float*)d_in[3];
  const float* wp   = (const float*)d_in[4];
  const float* g1   = (const float*)d_in[5];
  const float* b1   = (const float*)d_in[6];
  const float* fc1w = (const float*)d_in[7];
  const float* fc1b = (const float*)d_in[8];
  const float* fc2w = (const float*)d_in[9];
  const float* fc2b = (const float*)d_in[10];
  const float* g2   = (const float*)d_in[11];
  const float* b2   = (const float*)d_in[12];
  float* out = (float*)d_out;

  char* ws = (char*)d_ws;
  const size_t MB = 1024 * 1024;
  if (ws_size < 216 * MB) return;

  // ADJACENCY CONSTRAINT: qk_bh = [wq^T | wk^T] hi as ONE [4096][2048];
  // qk_bl likewise lo (split8's B operands span both).
  bf16* xh    = (bf16*)(ws + 0 * MB);
  bf16* xl    = (bf16*)(ws + 8 * MB);
  bf16* qk_bh = (bf16*)(ws + 16 * MB);   // 16MB
  bf16* qk_bl = (bf16*)(ws + 32 * MB);   // 16MB
  bf16* wvt   = (bf16*)(ws + 48 * MB);
  bf16* wpt   = (bf16*)(ws + 56 * MB);
  bf16* fc1t  = (bf16*)(ws + 64 * MB);   // 32MB
  bf16* fc2t  = (bf16*)(ws + 96 * MB);   // 32MB
  float* vtp  = (float*)(ws + 128 * MB); // 4x16MB vt partials
  bf16* vtb   = (bf16*)(ws + 192 * MB);  // 8MB
  bf16* qkh   = (bf16*)(ws + 128 * MB);  // 16MB (vtp dead after combine4)
  bf16* qkl   = (bf16*)(ws + 144 * MB);  // 16MB
  bf16* cc    = (bf16*)(ws + 200 * MB);  // 8MB concat
  float* aop  = (float*)(ws + 128 * MB); // 4x16MB (qk dead post-flash)
  float* h32  = (float*)(ws + 192 * MB); // 16MB (vtb dead post-flash)
  bf16*  hbf  = (bf16*)(ws + 208 * MB);  // 8MB
  bf16*  ff1  = (bf16*)(ws + 128 * MB);  // 32MB (aop dead after LN1)
  float* ffp  = (float*)(ws + 0 * MB);   // 4x16MB (x/qk_b dead)
  const long PSTR = 4194304L;

  // fused converts: wq/wk/wv transposes + x hi/lo split tail
  k_tcvt_qkv<<<dim3(2, 32, 48), 256, 0, stream>>>(wq, wk, wv, qk_bh, qk_bl,
                                                  wvt, x, xh, xl);
  k_tcvt<false><<<dim3(32, 32, 1), 256, 0, stream>>>(wp, wpt, nullptr, 2048, 2048);
  k_tcvt<false><<<dim3(128, 32, 1), 256, 0, stream>>>(fc1w, fc1t, nullptr, 2048, 8192);
  k_tcvt<false><<<dim3(32, 128, 1), 256, 0, stream>>>(fc2w, fc2t, nullptr, 8192, 2048);

  // V^T = wvt @ xh^T  (8-phase, split-K=4) -> combine to bf16 (own dispatch:
  // vtp must be dead before split8 writes qkh/qkl over its region)
  k_gemm8<0><<<dim3(8, 8, 4), 512, 0, stream>>>(
      wvt, xh, vtp, nullptr, nullptr, 2048, 2048, 2048, 4);
  k_combine4<<<4096, 256, 0, stream>>>(vtp, PSTR, vtb);
  // fused Q,K projection (8-phase split-precision)
  k_split8<<<dim3(16, 16), 512, 0, stream>>>(
      xh, xl, qk_bh, qk_bl, qkh, qkl, 2048, 4096, 2048,
      0.08838834764831845f, 2048);
  // attention -> concat
  k_flash<<<dim3(32, 16), 256, 0, stream>>>(qkh, qkl, qkh + 2048, qkl + 2048,
                                            vtb, cc);
  // out projection (8-phase, split-K=4)
  k_gemm8<0><<<dim3(8, 8, 4), 512, 0, stream>>>(
      cc, wpt, aop, nullptr, nullptr, 2048, 2048, 2048, 4);
  // h = LN(x + sum aop)
  k_add_ln<<<2048, 256, 0, stream>>>(x, aop, PSTR, 4, nullptr, g1, b1, h32, hbf);
  // ff1 = relu(h @ fc1 + b1)
  k_gemm8<2><<<dim3(32, 8, 1), 512, 0, stream>>>(
      hbf, fc1t, nullptr, ff1, fc1b, 2048, 8192, 2048, 1);
  // ff2 partials (8-phase, split-K=4 over K=8192)
  k_gemm8<0><<<dim3(8, 8, 4), 512, 0, stream>>>(
      ff1, fc2t, ffp, nullptr, nullptr, 2048, 2048, 8192, 4);
  // out = LN(h + sum ffp + fc2b)
  k_add_ln<<<2048, 256, 0, stream>>>(h32, ffp, PSTR, 4, fc2b, g2, b2, out, nullptr);
}

// Round 16
// 496.998 us; speedup vs baseline: 1.1086x; 1.0356x over previous
//
#include <hip/hip_runtime.h>

// TransformerBlock fused pipeline for MI355X (gfx950).
// SEQ=2048, D_MODEL=2048, H=16, DK=DV=128, DFF=8192. fp32 in/out.
//
// R16: split-K partials stored as bf16 (EPI=3) for vt/out-proj/fc2 --
// halves partial write+read traffic (~96MB saved ~= 10us). combine4/add_ln
// read bf16 partials, accumulate fp32. Numerics: worst case (out-proj,
// values O(22)) adds ~0.4% relative post-LN; margin 0.031 vs 0.109 holds.
// Everything else R15-exact.

typedef __bf16 bf16;
typedef __attribute__((ext_vector_type(8))) __bf16 bf16x8;
typedef __attribute__((ext_vector_type(4))) __bf16 bf16x4;
typedef __attribute__((ext_vector_type(4))) float f32x4;

#define MFMA(a, b, c) __builtin_amdgcn_mfma_f32_16x16x32_bf16((a), (b), (c), 0, 0, 0)
#define NEG_INF (-3.402823466e38f)

__device__ __forceinline__ void cp16(void* lds, const void* g) {
  __builtin_amdgcn_global_load_lds(
      (const __attribute__((address_space(1))) unsigned int*)g,
      (__attribute__((address_space(3))) unsigned int*)lds, 16, 0, 0);
}

#define SBAR() __builtin_amdgcn_sched_barrier(0)
#define GBAR()                              \
  do {                                      \
    asm volatile("" ::: "memory");          \
    __builtin_amdgcn_s_barrier();           \
    asm volatile("" ::: "memory");          \
  } while (0)
#define LGKM0()                                         \
  do {                                                  \
    asm volatile("s_waitcnt lgkmcnt(0)" ::: "memory");  \
    __builtin_amdgcn_sched_barrier(0);                  \
  } while (0)
#define VMC6()                                          \
  do {                                                  \
    asm volatile("s_waitcnt vmcnt(6)" ::: "memory");    \
    __builtin_amdgcn_sched_barrier(0);                  \
  } while (0)

// bijective XCD swizzle for 2D grids with (gx*gy)%8==0
__device__ __forceinline__ void xcd_swz(int& bx, int& by) {
  const int gx = gridDim.x, nwg = gx * gridDim.y;
  const int lid = by * gx + bx;
  const int swz = (lid & 7) * (nwg >> 3) + (lid >> 3);
  bx = swz % gx;
  by = swz / gx;
}

// ---------------- fused converts ----------------
__global__ void k_tcvt_qkv(const float* __restrict__ wq,
                           const float* __restrict__ wk,
                           const float* __restrict__ wv,
                           bf16* __restrict__ bh, bf16* __restrict__ bl,
                           bf16* __restrict__ vt,
                           const float* __restrict__ x,
                           bf16* __restrict__ xh, bf16* __restrict__ xl) {
  __shared__ float t[64][65];
  const long W4M = 4L * 1024 * 1024;
  int sel = blockIdx.z >> 4, zz = blockIdx.z & 15;
  const float* in = (sel == 0) ? wq : ((sel == 1) ? wk : wv);
  bf16* oh = (sel == 0) ? bh : ((sel == 1) ? bh + W4M : vt);
  bf16* ol = (sel == 0) ? bl : ((sel == 1) ? bl + W4M : nullptr);
  const int R = 2048, C = 128;
  long zoff = (long)zz * R * C;
  int c0 = blockIdx.x * 64, r0 = blockIdx.y * 64;
  int cc = threadIdx.x & 63, rr = threadIdx.x >> 6;
#pragma unroll
  for (int i = 0; i < 16; ++i) {
    int r = i * 4 + rr;
    t[r][cc] = in[zoff + (long)(r0 + r) * C + c0 + cc];
  }
  __syncthreads();
#pragma unroll
  for (int i = 0; i < 16; ++i) {
    int orow = i * 4 + rr;
    float v = t[cc][orow];
    long oidx = zoff + (long)(c0 + orow) * R + r0 + cc;
    bf16 hi = (bf16)v;
    oh[oidx] = hi;
    if (ol != nullptr) ol[oidx] = (bf16)(v - (float)hi);
  }
  long gtid = (long)(blockIdx.z * gridDim.y * gridDim.x +
                     blockIdx.y * gridDim.x + blockIdx.x) * 256 + threadIdx.x;
  for (long i = gtid; i < 1048576L; i += 786432L) {
    f32x4 v = ((const f32x4*)x)[i];
    bf16x4 h, l;
#pragma unroll
    for (int j = 0; j < 4; ++j) {
      bf16 hi = (bf16)v[j];
      h[j] = hi;
      l[j] = (bf16)(v[j] - (float)hi);
    }
    ((bf16x4*)xh)[i] = h;
    ((bf16x4*)xl)[i] = l;
  }
}

template <bool SPLIT>
__global__ void k_tcvt(const float* __restrict__ in, bf16* __restrict__ oh,
                       bf16* __restrict__ ol, int R, int C) {
  __shared__ float t[64][65];
  long zoff = (long)blockIdx.z * R * C;
  int c0 = blockIdx.x * 64, r0 = blockIdx.y * 64;
  int cc = threadIdx.x & 63, rr = threadIdx.x >> 6;
#pragma unroll
  for (int i = 0; i < 16; ++i) {
    int r = i * 4 + rr;
    t[r][cc] = in[zoff + (long)(r0 + r) * C + c0 + cc];
  }
  __syncthreads();
#pragma unroll
  for (int i = 0; i < 16; ++i) {
    int orow = i * 4 + rr;
    float v = t[cc][orow];
    long oidx = zoff + (long)(c0 + orow) * R + r0 + cc;
    bf16 hi = (bf16)v;
    oh[oidx] = hi;
    if (SPLIT) ol[oidx] = (bf16)(v - (float)hi);
  }
}

// combine 4 bf16 partials -> bf16 (fp32 accumulate)
__global__ void k_combine4(const bf16* __restrict__ p, long pstr,
                           bf16* __restrict__ o) {
  int i = blockIdx.x * 256 + threadIdx.x;
  f32x4 v;
#pragma unroll
  for (int j = 0; j < 4; ++j) v[j] = 0.f;
#pragma unroll
  for (int zz = 0; zz < 4; ++zz) {
    bf16x4 pb = ((const bf16x4*)(p + zz * pstr))[i];
#pragma unroll
    for (int j = 0; j < 4; ++j) v[j] += (float)pb[j];
  }
  bf16x4 ob;
#pragma unroll
  for (int j = 0; j < 4; ++j) ob[j] = (bf16)v[j];
  ((bf16x4*)o)[i] = ob;
}

// ---------------- 8-phase 256^2 GEMM (R6 value-verified) + XCD swizzle -----
// EPI: 0 = fp32 partial; 2 = relu(v+bias) bf16; 3 = bf16 partial at z*M*N.
template <int EPI>
__global__ __launch_bounds__(512, 1) void k_gemm8(
    const bf16* __restrict__ A, const bf16* __restrict__ B,
    float* __restrict__ Cf, bf16* __restrict__ Cb,
    const float* __restrict__ bias, int M, int N, int K, int nsplit) {
  __shared__ char lds[131072];
  const int tid = threadIdx.x, w = tid >> 6, l = tid & 63;
  const int l16 = l & 15, lg = l >> 4;
  const int wr = w >> 2, wc = w & 3;
  int bx = blockIdx.x, by = blockIdx.y;
  xcd_swz(bx, by);
  const long bm0 = (long)by * 256, bn0 = (long)bx * 256;
  const int z = blockIdx.z;
  const int ksz = K / nsplit, kbeg = z * ksz;
  const int nt = ksz >> 6;
  const long lK = K;

  const int srow = w * 8 + (l >> 3);
  const int sslot = (l & 7) ^ (l >> 3);

  auto STAGE = [&](int bufp, int isB, int h, int tt) {
    int tc = tt < nt ? tt : nt - 1;
    char* dst = lds + bufp * 65536 + isB * 32768 + h * 16384 + w * 1024;
    const bf16* G = isB ? B : A;
    long r0 = (isB ? bn0 : bm0) + h * 128 + srow;
    const bf16* src = G + r0 * lK + kbeg + tc * 64 + sslot * 8;
    cp16(dst, src);
    cp16(dst + 8192, src + 64 * lK);
  };
  auto LDA = [&](int bufp, int mf, int ks) -> bf16x8 {
    int inrow = (mf & 3) * 32 + wr * 16 + l16;
    int byo = bufp * 65536 + (mf >> 2) * 16384 + inrow * 128 +
              ((((ks << 2) + lg) ^ (inrow & 7)) << 4);
    return *(const bf16x8*)(lds + byo);
  };
  auto LDB = [&](int bufp, int nf, int ks) -> bf16x8 {
    int inrow = (nf & 1) * 64 + wc * 16 + l16;
    int byo = bufp * 65536 + 32768 + (nf >> 1) * 16384 + inrow * 128 +
              ((((ks << 2) + lg) ^ (inrow & 7)) << 4);
    return *(const bf16x8*)(lds + byo);
  };

  f32x4 acc[8][4];
#pragma unroll
  for (int mf = 0; mf < 8; ++mf)
#pragma unroll
    for (int nf = 0; nf < 4; ++nf)
#pragma unroll
      for (int j = 0; j < 4; ++j) acc[mf][nf][j] = 0.f;

  STAGE(0, 0, 0, 0);
  STAGE(0, 1, 0, 0);
  STAGE(0, 0, 1, 0);
  STAGE(0, 1, 1, 0);
  STAGE(1, 1, 0, 1);
  STAGE(1, 0, 1, 1);
  STAGE(1, 1, 1, 1);
  SBAR();
  VMC6();
  GBAR();

  bf16x8 a[4][2], b[2][2];
  for (int t = 0; t < nt; ++t) {
    const int cb = t & 1, nb = cb ^ 1;
#pragma unroll
    for (int mf = 0; mf < 4; ++mf)
#pragma unroll
      for (int ks = 0; ks < 2; ++ks) a[mf][ks] = LDA(cb, mf, ks);
#pragma unroll
    for (int nf = 0; nf < 2; ++nf)
#pragma unroll
      for (int ks = 0; ks < 2; ++ks) b[nf][ks] = LDB(cb, nf, ks);
    STAGE(nb, 0, 0, t + 1);
    SBAR();
    GBAR();
    LGKM0();
    __builtin_amdgcn_s_setprio(1);
#pragma unroll
    for (int mf = 0; mf < 4; ++mf)
#pragma unroll
      for (int nf = 0; nf < 2; ++nf)
#pragma unroll
        for (int ks = 0; ks < 2; ++ks)
          acc[mf][nf] = MFMA(a[mf][ks], b[nf][ks], acc[mf][nf]);
    __builtin_amdgcn_s_setprio(0);
    GBAR();
#pragma unroll
    for (int mf = 0; mf < 4; ++mf)
#pragma unroll
      for (int ks = 0; ks < 2; ++ks) a[mf][ks] = LDA(cb, mf + 4, ks);
    STAGE(cb, 1, 0, t + 2);
    SBAR();
    GBAR();
    LGKM0();
    __builtin_amdgcn_s_setprio(1);
#pragma unroll
    for (int mf = 0; mf < 4; ++mf)
#pragma unroll
      for (int nf = 0; nf < 2; ++nf)
#pragma unroll
        for (int ks = 0; ks < 2; ++ks)
          acc[mf + 4][nf] = MFMA(a[mf][ks], b[nf][ks], acc[mf + 4][nf]);
    __builtin_amdgcn_s_setprio(0);
    GBAR();
#pragma unroll
    for (int nf = 0; nf < 2; ++nf)
#pragma unroll
      for (int ks = 0; ks < 2; ++ks) b[nf][ks] = LDB(cb, nf + 2, ks);
    GBAR();
    LGKM0();
    __builtin_amdgcn_s_setprio(1);
#pragma unroll
    for (int mf = 0; mf < 4; ++mf)
#pragma unroll
      for (int nf = 0; nf < 2; ++nf)
#pragma unroll
        for (int ks = 0; ks < 2; ++ks)
          acc[mf + 4][nf + 2] = MFMA(a[mf][ks], b[nf][ks], acc[mf + 4][nf + 2]);
    __builtin_amdgcn_s_setprio(0);
    GBAR();
#pragma unroll
    for (int mf = 0; mf < 4; ++mf)
#pragma unroll
      for (int ks = 0; ks < 2; ++ks) a[mf][ks] = LDA(cb, mf, ks);
    STAGE(cb, 0, 1, t + 2);
    STAGE(cb, 1, 1, t + 2);
    SBAR();
    VMC6();
    GBAR();
    LGKM0();
    __builtin_amdgcn_s_setprio(1);
#pragma unroll
    for (int mf = 0; mf < 4; ++mf)
#pragma unroll
      for (int nf = 0; nf < 2; ++nf)
#pragma unroll
        for (int ks = 0; ks < 2; ++ks)
          acc[mf][nf + 2] = MFMA(a[mf][ks], b[nf][ks], acc[mf][nf + 2]);
    __builtin_amdgcn_s_setprio(0);
    GBAR();
  }
  asm volatile("s_waitcnt vmcnt(0) lgkmcnt(0)" ::: "memory");

#pragma unroll
  for (int mf = 0; mf < 8; ++mf)
#pragma unroll
    for (int nf = 0; nf < 4; ++nf) {
      long col = bn0 + nf * 64 + wc * 16 + l16;
      float bv = (EPI == 2) ? bias[col] : 0.f;
#pragma unroll
      for (int jj = 0; jj < 4; ++jj) {
        long row = bm0 + mf * 32 + wr * 16 + lg * 4 + jj;
        float v = acc[mf][nf][jj];
        if (EPI == 0) {
          Cf[(long)z * M * N + row * N + col] = v;
        } else if (EPI == 3) {
          Cb[(long)z * M * N + row * N + col] = (bf16)v;
        } else {
          v = fmaxf(v + bv, 0.f);
          Cb[row * N + col] = (bf16)v;
        }
      }
    }
}

// ---------------- 8-phase split-precision GEMM (QK proj) + XCD swizzle -----
__global__ __launch_bounds__(512, 1) void k_split8(
    const bf16* __restrict__ Ah_g, const bf16* __restrict__ Al_g,
    const bf16* __restrict__ Bh_g, const bf16* __restrict__ Bl_g,
    bf16* __restrict__ Ch, bf16* __restrict__ Cl,
    int M, int N, int K, float scale, int scale_ncols) {
  __shared__ char lds[98304];
  const int tid = threadIdx.x, w = tid >> 6, l = tid & 63;
  const int l16 = l & 15, lg = l >> 4;
  const int wr = w >> 2, wc = w & 3;
  int bx = blockIdx.x, by = blockIdx.y;
  xcd_swz(bx, by);
  const long bm0 = (long)by * 128, bn0 = (long)bx * 256;
  const int nt = K >> 5;
  const long lK = K;

  const int srcrow = tid >> 2;
  const int ss = (tid & 3) ^ ((tid >> 3) & 3);

  auto STG_A = [&](int bufp, int isLo, int tt) {
    int tc = tt < nt ? tt : nt - 1;
    char* dst = lds + bufp * 49152 + isLo * 8192 + tid * 16;
    const bf16* G = isLo ? Al_g : Ah_g;
    cp16(dst, &G[(bm0 + srcrow) * lK + tc * 32 + ss * 8]);
  };
  auto STG_B = [&](int bufp, int isLo, int half, int tt) {
    int tc = tt < nt ? tt : nt - 1;
    char* dst = lds + bufp * 49152 + 16384 + isLo * 16384 + half * 8192 + tid * 16;
    const bf16* G = isLo ? Bl_g : Bh_g;
    cp16(dst, &G[(bn0 + half * 128 + srcrow) * lK + tc * 32 + ss * 8]);
  };
  auto LDA8 = [&](int bufp, int mf, int isLo) -> bf16x8 {
    int row = mf * 32 + wr * 16 + l16;
    int byo = bufp * 49152 + isLo * 8192 + row * 64 +
              ((lg ^ ((row >> 1) & 3)) << 4);
    return *(const bf16x8*)(lds + byo);
  };
  auto LDB8 = [&](int bufp, int nf, int isLo) -> bf16x8 {
    int row = nf * 64 + wc * 16 + l16;
    int byo = bufp * 49152 + 16384 + isLo * 16384 + row * 64 +
              ((lg ^ ((row >> 1) & 3)) << 4);
    return *(const bf16x8*)(lds + byo);
  };

  f32x4 acc[4][4];
#pragma unroll
  for (int mf = 0; mf < 4; ++mf)
#pragma unroll
    for (int nf = 0; nf < 4; ++nf)
#pragma unroll
      for (int j = 0; j < 4; ++j) acc[mf][nf][j] = 0.f;

  STG_B(0, 0, 0, 0); STG_B(0, 1, 0, 0);
  STG_A(0, 0, 0);    STG_A(0, 1, 0);
  STG_B(0, 0, 1, 0); STG_B(0, 1, 1, 0);
  STG_B(1, 0, 0, 1); STG_B(1, 1, 0, 1);
  STG_A(1, 0, 1);    STG_A(1, 1, 1);
  STG_B(1, 0, 1, 1); STG_B(1, 1, 1, 1);
  SBAR();
  VMC6();
  GBAR();

  bf16x8 ah[4], al[4], bh[2], bl[2];
  for (int t = 0; t < nt; ++t) {
    const int cb = t & 1;
    // P1
#pragma unroll
    for (int mf = 0; mf < 2; ++mf) {
      ah[mf] = LDA8(cb, mf, 0);
      al[mf] = LDA8(cb, mf, 1);
    }
#pragma unroll
    for (int nf = 0; nf < 2; ++nf) {
      bh[nf] = LDB8(cb, nf, 0);
      bl[nf] = LDB8(cb, nf, 1);
    }
    SBAR();
    GBAR();
    LGKM0();
    __builtin_amdgcn_s_setprio(1);
#pragma unroll
    for (int mf = 0; mf < 2; ++mf)
#pragma unroll
      for (int nf = 0; nf < 2; ++nf) {
        acc[mf][nf] = MFMA(ah[mf], bh[nf], acc[mf][nf]);
        acc[mf][nf] = MFMA(ah[mf], bl[nf], acc[mf][nf]);
        acc[mf][nf] = MFMA(al[mf], bh[nf], acc[mf][nf]);
      }
    __builtin_amdgcn_s_setprio(0);
    GBAR();
    // P2
#pragma unroll
    for (int mf = 2; mf < 4; ++mf) {
      ah[mf] = LDA8(cb, mf, 0);
      al[mf] = LDA8(cb, mf, 1);
    }
    STG_B(cb, 0, 0, t + 2);
    STG_B(cb, 1, 0, t + 2);
    SBAR();
    GBAR();
    LGKM0();
    __builtin_amdgcn_s_setprio(1);
#pragma unroll
    for (int mf = 2; mf < 4; ++mf)
#pragma unroll
      for (int nf = 0; nf < 2; ++nf) {
        acc[mf][nf] = MFMA(ah[mf], bh[nf], acc[mf][nf]);
        acc[mf][nf] = MFMA(ah[mf], bl[nf], acc[mf][nf]);
        acc[mf][nf] = MFMA(al[mf], bh[nf], acc[mf][nf]);
      }
    __builtin_amdgcn_s_setprio(0);
    GBAR();
    // P3
#pragma unroll
    for (int nf = 0; nf < 2; ++nf) {
      bh[nf] = LDB8(cb, nf + 2, 0);
      bl[nf] = LDB8(cb, nf + 2, 1);
    }
    STG_A(cb, 0, t + 2);
    STG_A(cb, 1, t + 2);
    SBAR();
    GBAR();
    LGKM0();
    __builtin_amdgcn_s_setprio(1);
#pragma unroll
    for (int mf = 2; mf < 4; ++mf)
#pragma unroll
      for (int nf = 0; nf < 2; ++nf) {
        acc[mf][nf + 2] = MFMA(ah[mf], bh[nf], acc[mf][nf + 2]);
        acc[mf][nf + 2] = MFMA(ah[mf], bl[nf], acc[mf][nf + 2]);
        acc[mf][nf + 2] = MFMA(al[mf], bh[nf], acc[mf][nf + 2]);
      }
    __builtin_amdgcn_s_setprio(0);
    GBAR();
    // P4
    STG_B(cb, 0, 1, t + 2);
    STG_B(cb, 1, 1, t + 2);
    SBAR();
    VMC6();
    GBAR();
    __builtin_amdgcn_s_setprio(1);
#pragma unroll
    for (int mf = 0; mf < 2; ++mf)
#pragma unroll
      for (int nf = 0; nf < 2; ++nf) {
        acc[mf][nf + 2] = MFMA(ah[mf], bh[nf], acc[mf][nf + 2]);
        acc[mf][nf + 2] = MFMA(ah[mf], bl[nf], acc[mf][nf + 2]);
        acc[mf][nf + 2] = MFMA(al[mf], bh[nf], acc[mf][nf + 2]);
      }
    __builtin_amdgcn_s_setprio(0);
    GBAR();
  }
  asm volatile("s_waitcnt vmcnt(0) lgkmcnt(0)" ::: "memory");

#pragma unroll
  for (int mf = 0; mf < 4; ++mf)
#pragma unroll
    for (int nf = 0; nf < 4; ++nf) {
      long col = bn0 + nf * 64 + wc * 16 + l16;
      float sc = (col < scale_ncols) ? scale : 1.0f;
#pragma unroll
      for (int j = 0; j < 4; ++j) {
        long row = bm0 + mf * 32 + wr * 16 + lg * 4 + j;
        float v = acc[mf][nf][j] * sc;
        bf16 hi = (bf16)v;
        Ch[row * N + col] = hi;
        Cl[row * N + col] = (bf16)(v - (float)hi);
      }
    }
}

// ---------------- flash attention (R9-exact) ----------------
__global__ __launch_bounds__(256, 3) void k_flash(
    const bf16* __restrict__ Qh, const bf16* __restrict__ Ql,
    const bf16* __restrict__ Kh, const bf16* __restrict__ Kl,
    const bf16* __restrict__ Vt, bf16* __restrict__ Oc) {
  __shared__ bf16 sm[24576];
  bf16* sKh = sm;
  bf16* sKl = sm + 8192;
  bf16* sVt = sm + 16384;
  bf16* sP = sKl;
  const int tid = threadIdx.x, w = tid >> 6, l = tid & 63;
  const int l16 = l & 15, lg = l >> 4;
  const int head = blockIdx.y;
  const long q0 = (long)blockIdx.x * 64;

  bf16x8 qh_r[4], ql_r[4];
#pragma unroll
  for (int kk = 0; kk < 4; ++kk) {
    long off = (q0 + w * 16 + l16) * 4096 + head * 128 + kk * 32 + lg * 8;
    qh_r[kk] = *(const bf16x8*)&Qh[off];
    ql_r[kk] = *(const bf16x8*)&Ql[off];
  }

  f32x4 acc_o[8];
#pragma unroll
  for (int n = 0; n < 8; ++n)
#pragma unroll
    for (int j = 0; j < 4; ++j) acc_o[n][j] = 0.f;
  float mrow[4], lrow[4];
#pragma unroll
  for (int j = 0; j < 4; ++j) {
    mrow[j] = NEG_INF;
    lrow[j] = 0.f;
  }

  for (int t0 = 0; t0 < 2048; t0 += 64) {
    __syncthreads();
#pragma unroll
    for (int i = 0; i < 4; ++i) {
      int c = (w * 4 + i) * 64 + l;
      int rk = c >> 4, sk = (c & 15) ^ (rk & 7);
      long ko = (long)(t0 + rk) * 4096 + head * 128 + sk * 8;
      int db = (w * 4 + i) * 512;
      cp16(&sKh[db], &Kh[ko]);
      cp16(&sKl[db], &Kl[ko]);
      int rv = c >> 3, sv = (c & 7) ^ (rv & 7);
      long vo = (long)(head * 128 + rv) * 2048 + t0 + sv * 8;
      cp16(&sVt[db], &Vt[vo]);
    }
    __syncthreads();

    f32x4 s[4];
#pragma unroll
    for (int n = 0; n < 4; ++n)
#pragma unroll
      for (int j = 0; j < 4; ++j) s[n][j] = 0.f;
    __builtin_amdgcn_s_setprio(1);
#pragma unroll
    for (int kk = 0; kk < 4; ++kk) {
      bf16x8 bh[4], bl[4];
#pragma unroll
      for (int n = 0; n < 4; ++n) {
        int r = n * 16 + l16;
        int byo = r * 256 + (((kk * 4 + lg) ^ (r & 7)) << 4);
        bh[n] = *(const bf16x8*)((const char*)sKh + byo);
        bl[n] = *(const bf16x8*)((const char*)sKl + byo);
      }
#pragma unroll
      for (int n = 0; n < 4; ++n) {
        s[n] = MFMA(qh_r[kk], bh[n], s[n]);
        s[n] = MFMA(qh_r[kk], bl[n], s[n]);
        s[n] = MFMA(ql_r[kk], bh[n], s[n]);
      }
    }
    __builtin_amdgcn_s_setprio(0);
    __syncthreads();

#pragma unroll
    for (int j = 0; j < 4; ++j) {
      float mx = fmaxf(fmaxf(s[0][j], s[1][j]), fmaxf(s[2][j], s[3][j]));
      mx = fmaxf(mx, __shfl_xor(mx, 1));
      mx = fmaxf(mx, __shfl_xor(mx, 2));
      mx = fmaxf(mx, __shfl_xor(mx, 4));
      mx = fmaxf(mx, __shfl_xor(mx, 8));
      float mo = mrow[j];
      float mn = fmaxf(mo, mx);
      mrow[j] = mn;
      float f = __expf(mo - mn);
      int prow = w * 16 + lg * 4 + j;
      float ssum = 0.f;
#pragma unroll
      for (int n = 0; n < 4; ++n) {
        float p = __expf(s[n][j] - mn);
        ssum += p;
        int byo = prow * 128 + (((n * 16 + l16) * 2) ^ ((prow & 7) << 4));
        *(bf16*)((char*)sP + byo) = (bf16)p;
      }
      ssum += __shfl_xor(ssum, 1);
      ssum += __shfl_xor(ssum, 2);
      ssum += __shfl_xor(ssum, 4);
      ssum += __shfl_xor(ssum, 8);
      lrow[j] = lrow[j] * f + ssum;
#pragma unroll
      for (int n = 0; n < 8; ++n) acc_o[n][j] *= f;
    }

    __builtin_amdgcn_s_setprio(1);
#pragma unroll
    for (int kk = 0; kk < 2; ++kk) {
      bf16x8 pa, bv[8];
      {
        int r = w * 16 + l16;
        int byo = r * 128 + (((kk * 4 + lg) ^ (r & 7)) << 4);
        pa = *(const bf16x8*)((const char*)sP + byo);
      }
#pragma unroll
      for (int n = 0; n < 8; ++n) {
        int r = n * 16 + l16;
        int byo = r * 128 + (((kk * 4 + lg) ^ (r & 7)) << 4);
        bv[n] = *(const bf16x8*)((const char*)sVt + byo);
      }
#pragma unroll
      for (int n = 0; n < 8; ++n) acc_o[n] = MFMA(pa, bv[n], acc_o[n]);
    }
    __builtin_amdgcn_s_setprio(0);
  }

#pragma unroll
  for (int j = 0; j < 4; ++j) {
    float rinv = 1.f / lrow[j];
    long row = q0 + w * 16 + lg * 4 + j;
#pragma unroll
    for (int n = 0; n < 8; ++n)
      Oc[row * 2048 + head * 128 + n * 16 + l16] = (bf16)(acc_o[n][j] * rinv);
  }
}

// ---------------- residual + np bf16 partials + LayerNorm ----------------
__global__ __launch_bounds__(256) void k_add_ln(
    const float* __restrict__ a, const bf16* __restrict__ p, long pstr,
    int np, const float* __restrict__ bias, const float* __restrict__ g,
    const float* __restrict__ be, float* __restrict__ o32,
    bf16* __restrict__ obf) {
  __shared__ float red[8];
  int row = blockIdx.x, tid = threadIdx.x;
  const float* pa = a + (long)row * 2048;
  f32x4 v[2];
  float sum = 0.f, sq = 0.f;
#pragma unroll
  for (int i = 0; i < 2; ++i) {
    int idx = i * 1024 + tid * 4;
    v[i] = *(const f32x4*)(pa + idx);
    for (int zz = 0; zz < np; ++zz) {
      bf16x4 pb = *(const bf16x4*)(p + zz * pstr + (long)row * 2048 + idx);
#pragma unroll
      for (int j = 0; j < 4; ++j) v[i][j] += (float)pb[j];
    }
    if (bias != nullptr) v[i] += *(const f32x4*)(bias + idx);
#pragma unroll
    for (int j = 0; j < 4; ++j) {
      sum += v[i][j];
      sq += v[i][j] * v[i][j];
    }
  }
#pragma unroll
  for (int o = 1; o < 64; o <<= 1) {
    sum += __shfl_xor(sum, o);
    sq += __shfl_xor(sq, o);
  }
  int w = tid >> 6;
  if ((tid & 63) == 0) {
    red[w * 2] = sum;
    red[w * 2 + 1] = sq;
  }
  __syncthreads();
  sum = red[0] + red[2] + red[4] + red[6];
  sq = red[1] + red[3] + red[5] + red[7];
  float mu = sum * (1.f / 2048.f);
  float var = sq * (1.f / 2048.f) - mu * mu;
  float rs = rsqrtf(var + 1e-5f);
#pragma unroll
  for (int i = 0; i < 2; ++i) {
    int idx = i * 1024 + tid * 4;
    f32x4 vg = *(const f32x4*)(g + idx);
    f32x4 vb = *(const f32x4*)(be + idx);
    f32x4 o;
#pragma unroll
    for (int j = 0; j < 4; ++j) o[j] = (v[i][j] - mu) * rs * vg[j] + vb[j];
    *(f32x4*)(o32 + (long)row * 2048 + idx) = o;
    if (obf != nullptr) {
      bf16x4 ob;
#pragma unroll
      for (int j = 0; j < 4; ++j) ob[j] = (bf16)o[j];
      *(bf16x4*)(obf + (long)row * 2048 + idx) = ob;
    }
  }
}

// ---------------- launch ----------------
extern "C" void kernel_launch(void* const* d_in, const int* in_sizes, int n_in,
                              void* d_out, int out_size, void* d_ws, size_t ws_size,
                              hipStream_t stream) {
  const float* x    = (const float*)d_in[0];
  const float* wq   = (const float*)d_in[1];
  const float* wk   = (const float*)d_in[2];
  const float* wv   = (const float*)d_in[3];
  const float* wp   = (const float*)d_in[4];
  const float* g1   = (const float*)d_in[5];
  const float* b1   = (const float*)d_in[6];
  const float* fc1w = (const float*)d_in[7];
  const float* fc1b = (const float*)d_in[8];
  const float* fc2w = (const float*)d_in[9];
  const float* fc2b = (const float*)d_in[10];
  const float* g2   = (const float*)d_in[11];
  const float* b2   = (const float*)d_in[12];
  float* out = (float*)d_out;

  char* ws = (char*)d_ws;
  const size_t MB = 1024 * 1024;
  if (ws_size < 216 * MB) return;

  // ADJACENCY CONSTRAINT: qk_bh = [wq^T | wk^T] hi as ONE [4096][2048];
  // qk_bl likewise lo (split8's B operands span both).
  bf16* xh    = (bf16*)(ws + 0 * MB);
  bf16* xl    = (bf16*)(ws + 8 * MB);
  bf16* qk_bh = (bf16*)(ws + 16 * MB);   // 16MB
  bf16* qk_bl = (bf16*)(ws + 32 * MB);   // 16MB
  bf16* wvt   = (bf16*)(ws + 48 * MB);
  bf16* wpt   = (bf16*)(ws + 56 * MB);
  bf16* fc1t  = (bf16*)(ws + 64 * MB);   // 32MB
  bf16* fc2t  = (bf16*)(ws + 96 * MB);   // 32MB
  bf16* vtp   = (bf16*)(ws + 128 * MB);  // 4x8MB vt partials (bf16)
  bf16* vtb   = (bf16*)(ws + 192 * MB);  // 8MB
  bf16* qkh   = (bf16*)(ws + 128 * MB);  // 16MB (vtp dead after combine4)
  bf16* qkl   = (bf16*)(ws + 144 * MB);  // 16MB
  bf16* cc    = (bf16*)(ws + 200 * MB);  // 8MB concat
  bf16* aop   = (bf16*)(ws + 128 * MB);  // 4x8MB (qk dead post-flash)
  float* h32  = (float*)(ws + 192 * MB); // 16MB (vtb dead post-flash)
  bf16*  hbf  = (bf16*)(ws + 208 * MB);  // 8MB
  bf16*  ff1  = (bf16*)(ws + 128 * MB);  // 32MB (aop dead after LN1)
  bf16*  ffp  = (bf16*)(ws + 0 * MB);    // 4x8MB (x/qk_b dead)
  const long PSTR = 4194304L;            // partial stride in bf16 elems (8MB)

  // fused converts: wq/wk/wv transposes + x hi/lo split tail
  k_tcvt_qkv<<<dim3(2, 32, 48), 256, 0, stream>>>(wq, wk, wv, qk_bh, qk_bl,
                                                  wvt, x, xh, xl);
  k_tcvt<false><<<dim3(32, 32, 1), 256, 0, stream>>>(wp, wpt, nullptr, 2048, 2048);
  k_tcvt<false><<<dim3(128, 32, 1), 256, 0, stream>>>(fc1w, fc1t, nullptr, 2048, 8192);
  k_tcvt<false><<<dim3(32, 128, 1), 256, 0, stream>>>(fc2w, fc2t, nullptr, 8192, 2048);

  // V^T = wvt @ xh^T  (8-phase, split-K=4, bf16 partials) -> combine
  k_gemm8<3><<<dim3(8, 8, 4), 512, 0, stream>>>(
      wvt, xh, nullptr, vtp, nullptr, 2048, 2048, 2048, 4);
  k_combine4<<<4096, 256, 0, stream>>>(vtp, PSTR, vtb);
  // fused Q,K projection (8-phase split-precision)
  k_split8<<<dim3(16, 16), 512, 0, stream>>>(
      xh, xl, qk_bh, qk_bl, qkh, qkl, 2048, 4096, 2048,
      0.08838834764831845f, 2048);
  // attention -> concat
  k_flash<<<dim3(32, 16), 256, 0, stream>>>(qkh, qkl, qkh + 2048, qkl + 2048,
                                            vtb, cc);
  // out projection (8-phase, split-K=4, bf16 partials)
  k_gemm8<3><<<dim3(8, 8, 4), 512, 0, stream>>>(
      cc, wpt, nullptr, aop, nullptr, 2048, 2048, 2048, 4);
  // h = LN(x + sum aop)
  k_add_ln<<<2048, 256, 0, stream>>>(x, aop, PSTR, 4, nullptr, g1, b1, h32, hbf);
  // ff1 = relu(h @ fc1 + b1)
  k_gemm8<2><<<dim3(32, 8, 1), 512, 0, stream>>>(
      hbf, fc1t, nullptr, ff1, fc1b, 2048, 8192, 2048, 1);
  // ff2 partials (8-phase, split-K=4 over K=8192, bf16 partials)
  k_gemm8<3><<<dim3(8, 8, 4), 512, 0, stream>>>(
      ff1, fc2t, nullptr, ffp, nullptr, 2048, 2048, 8192, 4);
  // out = LN(h + sum ffp + fc2b)
  k_add_ln<<<2048, 256, 0, stream>>>(h32, ffp, PSTR, 4, fc2b, g2, b2, out, nullptr);
}